// Round 1
// baseline (435.010 us; speedup 1.0000x reference)
//
#include <hip/hip_runtime.h>
#include <cstddef>

#define SQLEN 2048
#define DMODEL 2048
#define NHEADS 16
#define DHEAD 128

typedef __attribute__((ext_vector_type(8))) short bf16x8;
typedef __attribute__((ext_vector_type(4))) float floatx4;

__device__ __forceinline__ unsigned short f2bf(float f) {
  union { float f; unsigned u; } c; c.f = f;
  unsigned u = c.u;
  unsigned r = u + 0x7fffu + ((u >> 16) & 1u);
  return (unsigned short)(r >> 16);
}
__device__ __forceinline__ float bf2f(unsigned short s) {
  union { unsigned u; float f; } c; c.u = ((unsigned)s) << 16;
  return c.f;
}

// ---------------- fp32 -> bf16 convert (vectorized) -------------------------
__global__ __launch_bounds__(256) void f2b_kernel(const float4* __restrict__ in,
                                                  ushort4* __restrict__ out) {
  int i = blockIdx.x * 256 + threadIdx.x;
  float4 v = in[i];
  ushort4 o;
  o.x = f2bf(v.x); o.y = f2bf(v.y); o.z = f2bf(v.z); o.w = f2bf(v.w);
  out[i] = o;
}

// two-array variant (two tensors in one launch)
__global__ __launch_bounds__(256) void f2b2_kernel(const float4* __restrict__ in0,
                                                   ushort4* __restrict__ out0,
                                                   const float4* __restrict__ in1,
                                                   ushort4* __restrict__ out1,
                                                   int half_blocks) {
  int b = blockIdx.x;
  const float4* in = (b < half_blocks) ? in0 : in1;
  ushort4* out = (b < half_blocks) ? out0 : out1;
  int i = (b < half_blocks ? b : b - half_blocks) * 256 + threadIdx.x;
  float4 v = in[i];
  ushort4 o;
  o.x = f2bf(v.x); o.y = f2bf(v.y); o.z = f2bf(v.z); o.w = f2bf(v.w);
  out[i] = o;
}

// ---------------- bf16 MFMA GEMM: C[M,N] = A[M,K] @ B[N,K]^T ----------------
__global__ __launch_bounds__(256) void gemm_bf16_nt(const unsigned short* __restrict__ A,
                                                    const unsigned short* __restrict__ B,
                                                    float* __restrict__ C,
                                                    int M, int N, int K) {
  __shared__ __align__(16) unsigned short As[128 * 32];
  __shared__ __align__(16) unsigned short Bs[128 * 32];
  int tid = threadIdx.x;
  int wave = tid >> 6;
  int lane = tid & 63;
  int wm = wave >> 1, wn = wave & 1;
  int quad = lane >> 4, m16 = lane & 15;
  int row0 = blockIdx.y * 128, col0 = blockIdx.x * 128;

  floatx4 acc[4][4];
#pragma unroll
  for (int i = 0; i < 4; i++)
#pragma unroll
    for (int j = 0; j < 4; j++) acc[i][j] = (floatx4){0.f, 0.f, 0.f, 0.f};

  int c0 = tid, c1 = tid + 256;
  int r0c = c0 >> 2, q0c = (c0 & 3) * 8;
  int r1c = c1 >> 2, q1c = (c1 & 3) * 8;

  const size_t sK = (size_t)K;
  for (int k0 = 0; k0 < K; k0 += 32) {
    __builtin_amdgcn_global_load_lds(
        (const __attribute__((address_space(1))) unsigned int*)(A + (size_t)(row0 + r0c) * sK + k0 + q0c),
        (__attribute__((address_space(3))) unsigned int*)(As + c0 * 8), 16, 0, 0);
    __builtin_amdgcn_global_load_lds(
        (const __attribute__((address_space(1))) unsigned int*)(A + (size_t)(row0 + r1c) * sK + k0 + q1c),
        (__attribute__((address_space(3))) unsigned int*)(As + c1 * 8), 16, 0, 0);
    __builtin_amdgcn_global_load_lds(
        (const __attribute__((address_space(1))) unsigned int*)(B + (size_t)(col0 + r0c) * sK + k0 + q0c),
        (__attribute__((address_space(3))) unsigned int*)(Bs + c0 * 8), 16, 0, 0);
    __builtin_amdgcn_global_load_lds(
        (const __attribute__((address_space(1))) unsigned int*)(B + (size_t)(col0 + r1c) * sK + k0 + q1c),
        (__attribute__((address_space(3))) unsigned int*)(Bs + c1 * 8), 16, 0, 0);
    __syncthreads();

    bf16x8 af[4], bfr[4];
#pragma unroll
    for (int i = 0; i < 4; i++)
      af[i] = *(const bf16x8*)(As + (wm * 64 + i * 16 + m16) * 32 + quad * 8);
#pragma unroll
    for (int j = 0; j < 4; j++)
      bfr[j] = *(const bf16x8*)(Bs + (wn * 64 + j * 16 + m16) * 32 + quad * 8);
#pragma unroll
    for (int i = 0; i < 4; i++)
#pragma unroll
      for (int j = 0; j < 4; j++)
        acc[i][j] = __builtin_amdgcn_mfma_f32_16x16x32_bf16(af[i], bfr[j], acc[i][j], 0, 0, 0);
    __syncthreads();
  }

#pragma unroll
  for (int i = 0; i < 4; i++) {
#pragma unroll
    for (int j = 0; j < 4; j++) {
      int rr = row0 + wm * 64 + i * 16 + quad * 4;
      int cc = col0 + wn * 64 + j * 16 + m16;
#pragma unroll
      for (int r = 0; r < 4; r++)
        C[(size_t)(rr + r) * N + cc] = acc[i][j][r];
    }
  }
}

// ------- gate GEMM with fused swish*rn epilogue, bf16 output ---------------
__global__ __launch_bounds__(256) void gemm_swish_nt(const unsigned short* __restrict__ A,
                                                     const unsigned short* __restrict__ B,
                                                     const float* __restrict__ rn,
                                                     unsigned short* __restrict__ Hb,
                                                     int M, int N, int K) {
  __shared__ __align__(16) unsigned short As[128 * 32];
  __shared__ __align__(16) unsigned short Bs[128 * 32];
  int tid = threadIdx.x;
  int wave = tid >> 6;
  int lane = tid & 63;
  int wm = wave >> 1, wn = wave & 1;
  int quad = lane >> 4, m16 = lane & 15;
  int row0 = blockIdx.y * 128, col0 = blockIdx.x * 128;

  floatx4 acc[4][4];
#pragma unroll
  for (int i = 0; i < 4; i++)
#pragma unroll
    for (int j = 0; j < 4; j++) acc[i][j] = (floatx4){0.f, 0.f, 0.f, 0.f};

  int c0 = tid, c1 = tid + 256;
  int r0c = c0 >> 2, q0c = (c0 & 3) * 8;
  int r1c = c1 >> 2, q1c = (c1 & 3) * 8;

  const size_t sK = (size_t)K;
  for (int k0 = 0; k0 < K; k0 += 32) {
    __builtin_amdgcn_global_load_lds(
        (const __attribute__((address_space(1))) unsigned int*)(A + (size_t)(row0 + r0c) * sK + k0 + q0c),
        (__attribute__((address_space(3))) unsigned int*)(As + c0 * 8), 16, 0, 0);
    __builtin_amdgcn_global_load_lds(
        (const __attribute__((address_space(1))) unsigned int*)(A + (size_t)(row0 + r1c) * sK + k0 + q1c),
        (__attribute__((address_space(3))) unsigned int*)(As + c1 * 8), 16, 0, 0);
    __builtin_amdgcn_global_load_lds(
        (const __attribute__((address_space(1))) unsigned int*)(B + (size_t)(col0 + r0c) * sK + k0 + q0c),
        (__attribute__((address_space(3))) unsigned int*)(Bs + c0 * 8), 16, 0, 0);
    __builtin_amdgcn_global_load_lds(
        (const __attribute__((address_space(1))) unsigned int*)(B + (size_t)(col0 + r1c) * sK + k0 + q1c),
        (__attribute__((address_space(3))) unsigned int*)(Bs + c1 * 8), 16, 0, 0);
    __syncthreads();

    bf16x8 af[4], bfr[4];
#pragma unroll
    for (int i = 0; i < 4; i++)
      af[i] = *(const bf16x8*)(As + (wm * 64 + i * 16 + m16) * 32 + quad * 8);
#pragma unroll
    for (int j = 0; j < 4; j++)
      bfr[j] = *(const bf16x8*)(Bs + (wn * 64 + j * 16 + m16) * 32 + quad * 8);
#pragma unroll
    for (int i = 0; i < 4; i++)
#pragma unroll
      for (int j = 0; j < 4; j++)
        acc[i][j] = __builtin_amdgcn_mfma_f32_16x16x32_bf16(af[i], bfr[j], acc[i][j], 0, 0, 0);
    __syncthreads();
  }

#pragma unroll
  for (int i = 0; i < 4; i++) {
#pragma unroll
    for (int j = 0; j < 4; j++) {
      int rr = row0 + wm * 64 + i * 16 + quad * 4;
      int cc = col0 + wn * 64 + j * 16 + m16;
#pragma unroll
      for (int r = 0; r < 4; r++) {
        float g = acc[i][j][r];
        float rv = rn[(size_t)(rr + r) * N + cc];
        float hh = g / (1.f + __expf(-g)) * rv;
        Hb[(size_t)(rr + r) * N + cc] = f2bf(hh);
      }
    }
  }
}

// ---------------- alpha: block = 4 t-rows staged in LDS, loop 16 heads ------
__global__ __launch_bounds__(256) void alpha_kernel(const float* __restrict__ x,
                                                    const float* __restrict__ W_alpha,
                                                    const float* __restrict__ b_alpha,
                                                    const float* __restrict__ alpha_base,
                                                    float* __restrict__ a_raw) {
  __shared__ float xs[4][2048];
  int tid = threadIdx.x;
  int t0 = blockIdx.x * 4;
#pragma unroll
  for (int p = 0; p < 8; p++) {
    int idx = tid + p * 256;
    int row = idx >> 9, c4 = idx & 511;
    *(float4*)&xs[row][c4 * 4] = *(const float4*)(x + (size_t)(t0 + row) * DMODEL + c4 * 4);
  }
  __syncthreads();
  int w = tid >> 6, lane = tid & 63;
  int t = t0 + w;
#pragma unroll
  for (int h = 0; h < NHEADS; h++) {
    const float4* wr = (const float4*)(W_alpha + (size_t)h * DMODEL);
    float s = 0.f;
#pragma unroll
    for (int i = lane; i < 512; i += 64) {
      float4 a = *(const float4*)&xs[w][i * 4];
      float4 b = wr[i];
      s += a.x * b.x + a.y * b.y + a.z * b.z + a.w * b.w;
    }
#pragma unroll
    for (int off = 32; off > 0; off >>= 1) s += __shfl_down(s, off);
    if (lane == 0) {
      float sig = 1.f / (1.f + __expf(-(s + b_alpha[h])));
      a_raw[(size_t)h * SQLEN + t] = alpha_base[h] * 8.f * sig;
    }
  }
}

// ---------------- cumsum ----------------------------------------------------
__global__ __launch_bounds__(256) void cumsum_kernel(const float* __restrict__ a_raw,
                                                     float* __restrict__ A) {
  int h = blockIdx.x;
  __shared__ float part[256];
  int tid = threadIdx.x;
  float v[8];
  float s = 0.f;
#pragma unroll
  for (int i = 0; i < 8; i++) {
    v[i] = a_raw[(size_t)h * SQLEN + tid * 8 + i];
    s += v[i];
  }
  part[tid] = s;
  __syncthreads();
  for (int off = 1; off < 256; off <<= 1) {
    float tmp = (tid >= off) ? part[tid - off] : 0.f;
    __syncthreads();
    part[tid] += tmp;
    __syncthreads();
  }
  float run = (tid > 0) ? part[tid - 1] : 0.f;
#pragma unroll
  for (int i = 0; i < 8; i++) {
    run += v[i];
    A[(size_t)h * SQLEN + tid * 8 + i] = run;
  }
}

// ---------------- xPos: emit q,k,v directly as bf16 [h][t][d] ---------------
__global__ __launch_bounds__(256) void xpos_kernel(const float* __restrict__ qkv,
                                                   const float* __restrict__ a_raw,
                                                   const int* __restrict__ offset_p,
                                                   unsigned short* __restrict__ qb,
                                                   unsigned short* __restrict__ kb,
                                                   unsigned short* __restrict__ vb) {
  int idx = blockIdx.x * 256 + threadIdx.x;
  int j = idx & 63;
  int t = (idx >> 6) & 2047;
  int h = idx >> 17;
  float pos = (float)(t + offset_p[0]);
  float freq = exp2f(-(float)j * (13.287712379549449f / 64.f));
  float ang = pos * freq;
  float sn = __sinf(ang), cs = __cosf(ang);
  float zeta = (2.f * (float)j + 51.2f) / 179.2f;
  float lzp = __log2f(zeta) * pos * (1.f / 512.f);
  float sc = exp2f(lzp);
  float sci = exp2f(-lzp);
  const float* row = qkv + (size_t)t * (3 * DMODEL);
  int base = h * DHEAD + j;
  float q1 = row[base], q2 = row[base + 64];
  float k1 = row[DMODEL + base], k2 = row[DMODEL + base + 64];
  float v1 = row[2 * DMODEL + base], v2 = row[2 * DMODEL + base + 64];
  size_t o = ((size_t)h * SQLEN + t) * DHEAD + j;
  qb[o] = f2bf((q1 * cs - q2 * sn) * sc);
  qb[o + 64] = f2bf((q2 * cs + q1 * sn) * sc);
  float km = (1.f - __expf(a_raw[(size_t)h * SQLEN + t])) * sci;
  kb[o] = f2bf((k1 * cs - k2 * sn) * km);
  kb[o + 64] = f2bf((k2 * cs + k1 * sn) * km);
  vb[o] = f2bf(v1);
  vb[o + 64] = f2bf(v2);
}

// ------- transpose kb/vb [h][t][d] -> [h][d][t]; k gets exp(B-A[t]) scale ---
__global__ __launch_bounds__(256) void transpose_kv_kernel(const unsigned short* __restrict__ kb,
                                                           const unsigned short* __restrict__ vb,
                                                           const float* __restrict__ A,
                                                           unsigned short* __restrict__ kT,
                                                           unsigned short* __restrict__ vT) {
  __shared__ __align__(16) unsigned short tile[64][72];
  int h = blockIdx.z >> 1, sel = blockIdx.z & 1;
  int t0 = blockIdx.x * 64, d0 = blockIdx.y * 64;
  int tid = threadIdx.x;
  const unsigned short* src = (sel ? vb : kb) + ((size_t)h * SQLEN + t0) * DHEAD + d0;
  unsigned short* dst = (sel ? vT : kT) + (size_t)h * (DHEAD * SQLEN) + (size_t)d0 * SQLEN + t0;
  float B = A[(size_t)h * SQLEN + SQLEN - 1];
#pragma unroll
  for (int p = 0; p < 2; p++) {
    int c = tid + p * 256;
    int r = c >> 3, off = (c & 7) * 8;
    bf16x8 in = *(const bf16x8*)(src + (size_t)r * DHEAD + off);
    if (!sel) {
      float w = __expf(B - A[(size_t)h * SQLEN + t0 + r]);
      bf16x8 o;
#pragma unroll
      for (int j = 0; j < 8; j++) o[j] = (short)f2bf(bf2f((unsigned short)in[j]) * w);
      *(bf16x8*)&tile[r][off] = o;
    } else {
      *(bf16x8*)&tile[r][off] = in;
    }
  }
  __syncthreads();
#pragma unroll
  for (int p = 0; p < 2; p++) {
    int c = tid + p * 256;
    int dr = c >> 3, toff = (c & 7) * 8;
    bf16x8 o;
#pragma unroll
    for (int j = 0; j < 8; j++) o[j] = (short)tile[toff + j][dr];
    *(bf16x8*)(dst + (size_t)dr * SQLEN + toff) = o;
  }
}

// ---------------- transpose state -> stT bf16 [h][e][d] ---------------------
__global__ __launch_bounds__(256) void transpose_state_kernel(const float* __restrict__ st,
                                                              unsigned short* __restrict__ stT) {
  __shared__ float tile[64][65];
  int h = blockIdx.z, d0 = blockIdx.x * 64, e0 = blockIdx.y * 64;
  int tid = threadIdx.x;
  const float* src = st + (size_t)h * 16384 + (size_t)d0 * DHEAD + e0;
#pragma unroll
  for (int p = 0; p < 4; p++) {
    int idx = tid + p * 256;
    int r = idx >> 4, c = (idx & 15) * 4;
    float4 f = *(const float4*)(src + (size_t)r * DHEAD + c);
    tile[r][c] = f.x; tile[r][c + 1] = f.y; tile[r][c + 2] = f.z; tile[r][c + 3] = f.w;
  }
  __syncthreads();
  unsigned short* dst = stT + (size_t)h * 16384 + (size_t)e0 * DHEAD + d0;
#pragma unroll
  for (int p = 0; p < 2; p++) {
    int idx = tid + p * 256;
    int er = idx >> 3, doff = (idx & 7) * 8;
    bf16x8 o;
#pragma unroll
    for (int j = 0; j < 8; j++) o[j] = (short)f2bf(tile[doff + j][er]);
    *(bf16x8*)(dst + (size_t)er * DHEAD + doff) = o;
  }
}

// ---------------- retention v3: fused group-norm epilogue -------------------
// Direct-register q fragments (no qs LDS). Decay on S regs. GN per (row,head)
// tile = exactly this block's 64x128 output. Writes rn fp32 + rnb bf16.
__global__ __launch_bounds__(256) void retention_mfma(const unsigned short* __restrict__ qb,
                                                      const unsigned short* __restrict__ kb,
                                                      const unsigned short* __restrict__ vT,
                                                      const unsigned short* __restrict__ stT,
                                                      const float* __restrict__ A,
                                                      const float* __restrict__ gn_w,
                                                      const float* __restrict__ gn_b,
                                                      float* __restrict__ rn,
                                                      unsigned short* __restrict__ rnb) {
  __shared__ __align__(16) unsigned short ks[64 * 128];
  __shared__ __align__(16) unsigned short vs[128 * 64];
  __shared__ __align__(16) unsigned short Ss[64 * 72];
  __shared__ float djs[64];
  int h = blockIdx.x;
  int i0 = blockIdx.y * 64;
  int tid = threadIdx.x;
  int wave = tid >> 6, lane = tid & 63, quad = lane >> 4, m16 = lane & 15;
  const float* Ah = A + (size_t)h * SQLEN;
  float c = Ah[i0];
  int rq = wave * 16 + m16;

  // direct q fragment loads (read-once)
  const unsigned short* qh = qb + ((size_t)h * SQLEN + i0 + rq) * DHEAD;
  bf16x8 qf[4];
#pragma unroll
  for (int dc = 0; dc < 4; dc++)
    qf[dc] = *(const bf16x8*)(qh + dc * 32 + quad * 8);
  float ei = __expf(Ah[i0 + rq] - c);

  // groupnorm weights for this lane's columns
  float wg[8], bg[8];
#pragma unroll
  for (int et = 0; et < 8; et++) {
    int col = h * DHEAD + et * 16 + m16;
    wg[et] = gn_w[col];
    bg[et] = gn_b[col];
  }

  floatx4 acc[8];
#pragma unroll
  for (int et = 0; et < 8; et++) acc[et] = (floatx4){0.f, 0.f, 0.f, 0.f};

  // cross term with initial state: exp(Ai) * q @ stT
  if (c > -87.f) {
    const unsigned short* sp = stT + (size_t)h * 16384;
    float ecr[4];
#pragma unroll
    for (int r = 0; r < 4; r++) ecr[r] = __expf(Ah[i0 + wave * 16 + quad * 4 + r]);
#pragma unroll
    for (int et = 0; et < 8; et++) {
#pragma unroll
      for (int dc = 0; dc < 4; dc++) {
        bf16x8 sf = *(const bf16x8*)(sp + (et * 16 + m16) * DHEAD + dc * 32 + quad * 8);
        acc[et] = __builtin_amdgcn_mfma_f32_16x16x32_bf16(qf[dc], sf, acc[et], 0, 0, 0);
      }
#pragma unroll
      for (int r = 0; r < 4; r++) acc[et][r] *= ecr[r];
    }
  }

  for (int j0 = 0; j0 <= i0; j0 += 64) {
    if (c - Ah[j0 + 63] < -87.f) continue;  // whole tile underflows
    __syncthreads();
    const unsigned short* kh = kb + ((size_t)h * SQLEN + j0) * DHEAD;
    const unsigned short* vh = vT + (size_t)h * (DHEAD * SQLEN) + j0;
#pragma unroll
    for (int p = 0; p < 4; p++) {
      int cch = tid + p * 256;
      int r = cch >> 4, kp = (cch & 15) ^ (r & 7);
      __builtin_amdgcn_global_load_lds(
          (const __attribute__((address_space(1))) unsigned int*)(kh + (size_t)r * DHEAD + kp * 8),
          (__attribute__((address_space(3))) unsigned int*)(ks + cch * 8), 16, 0, 0);
      int e = cch >> 3, tp = (cch & 7) ^ (e & 7);
      __builtin_amdgcn_global_load_lds(
          (const __attribute__((address_space(1))) unsigned int*)(vh + (size_t)e * SQLEN + tp * 8),
          (__attribute__((address_space(3))) unsigned int*)(vs + cch * 8), 16, 0, 0);
    }
    if (tid < 64) djs[tid] = __expf(c - Ah[j0 + tid]);
    __syncthreads();

    bool diag = (j0 == i0);
#pragma unroll
    for (int jt = 0; jt < 4; jt++) {
      floatx4 s = (floatx4){0.f, 0.f, 0.f, 0.f};
#pragma unroll
      for (int dc = 0; dc < 4; dc++) {
        int rk = jt * 16 + m16;
        bf16x8 kf = *(const bf16x8*)(ks + rk * 128 + (((dc * 4 + quad) ^ (rk & 7)) * 8));
        s = __builtin_amdgcn_mfma_f32_16x16x32_bf16(kf, qf[dc], s, 0, 0, 0);
      }
      int jb = jt * 16 + quad * 4;
      float4 dj4 = *(const float4*)&djs[jb];
      ushort4 pk;
      pk.x = f2bf((diag && (jb + 0 > rq)) ? 0.f : s[0] * ei * dj4.x);
      pk.y = f2bf((diag && (jb + 1 > rq)) ? 0.f : s[1] * ei * dj4.y);
      pk.z = f2bf((diag && (jb + 2 > rq)) ? 0.f : s[2] * ei * dj4.z);
      pk.w = f2bf((diag && (jb + 3 > rq)) ? 0.f : s[3] * ei * dj4.w);
      *(ushort4*)(Ss + rq * 72 + jb) = pk;
    }

    // PV (wave-local S rows)
    bf16x8 sfr[2];
#pragma unroll
    for (int kc = 0; kc < 2; kc++)
      sfr[kc] = *(const bf16x8*)(Ss + rq * 72 + kc * 32 + quad * 8);
#pragma unroll
    for (int et = 0; et < 8; et++) {
#pragma unroll
      for (int kc = 0; kc < 2; kc++) {
        int e = et * 16 + m16;
        bf16x8 vf = *(const bf16x8*)(vs + e * 64 + (((kc * 4 + quad) ^ (e & 7)) * 8));
        acc[et] = __builtin_amdgcn_mfma_f32_16x16x32_bf16(sfr[kc], vf, acc[et], 0, 0, 0);
      }
    }
  }

  // fused group norm: stats across 16-lane m16 group x 8 et regs, per r
#pragma unroll
  for (int r = 0; r < 4; r++) {
    float s = 0.f, ss = 0.f;
#pragma unroll
    for (int et = 0; et < 8; et++) {
      float v = acc[et][r];
      s += v; ss += v * v;
    }
#pragma unroll
    for (int off = 8; off > 0; off >>= 1) {
      s += __shfl_xor(s, off);
      ss += __shfl_xor(ss, off);
    }
    float mu = s * (1.f / 128.f);
    float var = ss * (1.f / 128.f) - mu * mu;
    float inv = rsqrtf(var + 1e-5f);
    int row = i0 + wave * 16 + quad * 4 + r;
    size_t o = (size_t)row * DMODEL + h * DHEAD;
#pragma unroll
    for (int et = 0; et < 8; et++) {
      float rv = (acc[et][r] - mu) * inv * wg[et] + bg[et];
      rn[o + et * 16 + m16] = rv;
      rnb[o + et * 16 + m16] = f2bf(rv);
    }
  }
}

// -------- new_state GEMM: P[h,chunk] = kT_s[:,krange] @ vT[:,krange]^T ------
__global__ __launch_bounds__(256) void state_gemm(const unsigned short* __restrict__ kT,
                                                  const unsigned short* __restrict__ vT,
                                                  float* __restrict__ P) {
  __shared__ __align__(16) unsigned short As[128 * 32];
  __shared__ __align__(16) unsigned short Bs[128 * 32];
  int chunk = blockIdx.x, h = blockIdx.y;
  int tid = threadIdx.x;
  int wave = tid >> 6, lane = tid & 63;
  int wm = wave >> 1, wn = wave & 1;
  int quad = lane >> 4, m16 = lane & 15;
  const unsigned short* Ab = kT + (size_t)h * (DHEAD * SQLEN);
  const unsigned short* Bb = vT + (size_t)h * (DHEAD * SQLEN);

  floatx4 acc[4][4];
#pragma unroll
  for (int i = 0; i < 4; i++)
#pragma unroll
    for (int j = 0; j < 4; j++) acc[i][j] = (floatx4){0.f, 0.f, 0.f, 0.f};

  int c0 = tid, c1 = tid + 256;
  int r0c = c0 >> 2, q0c = (c0 & 3) * 8;
  int r1c = c1 >> 2, q1c = (c1 & 3) * 8;

  for (int k0 = chunk * 256; k0 < chunk * 256 + 256; k0 += 32) {
    __builtin_amdgcn_global_load_lds(
        (const __attribute__((address_space(1))) unsigned int*)(Ab + (size_t)r0c * SQLEN + k0 + q0c),
        (__attribute__((address_space(3))) unsigned int*)(As + c0 * 8), 16, 0, 0);
    __builtin_amdgcn_global_load_lds(
        (const __attribute__((address_space(1))) unsigned int*)(Ab + (size_t)r1c * SQLEN + k0 + q1c),
        (__attribute__((address_space(3))) unsigned int*)(As + c1 * 8), 16, 0, 0);
    __builtin_amdgcn_global_load_lds(
        (const __attribute__((address_space(1))) unsigned int*)(Bb + (size_t)r0c * SQLEN + k0 + q0c),
        (__attribute__((address_space(3))) unsigned int*)(Bs + c0 * 8), 16, 0, 0);
    __builtin_amdgcn_global_load_lds(
        (const __attribute__((address_space(1))) unsigned int*)(Bb + (size_t)r1c * SQLEN + k0 + q1c),
        (__attribute__((address_space(3))) unsigned int*)(Bs + c1 * 8), 16, 0, 0);
    __syncthreads();

    bf16x8 af[4], bfr[4];
#pragma unroll
    for (int i = 0; i < 4; i++)
      af[i] = *(const bf16x8*)(As + (wm * 64 + i * 16 + m16) * 32 + quad * 8);
#pragma unroll
    for (int j = 0; j < 4; j++)
      bfr[j] = *(const bf16x8*)(Bs + (wn * 64 + j * 16 + m16) * 32 + quad * 8);
#pragma unroll
    for (int i = 0; i < 4; i++)
#pragma unroll
      for (int j = 0; j < 4; j++)
        acc[i][j] = __builtin_amdgcn_mfma_f32_16x16x32_bf16(af[i], bfr[j], acc[i][j], 0, 0, 0);
    __syncthreads();
  }

  float* Pp = P + (size_t)(h * 8 + chunk) * 16384;
#pragma unroll
  for (int i = 0; i < 4; i++)
#pragma unroll
    for (int j = 0; j < 4; j++) {
      int rr = wm * 64 + i * 16 + quad * 4;
      int cc = wn * 64 + j * 16 + m16;
#pragma unroll
      for (int r = 0; r < 4; r++)
        Pp[(size_t)(rr + r) * DHEAD + cc] = acc[i][j][r];
    }
}

__global__ __launch_bounds__(256) void state_combine(const float* __restrict__ P,
                                                     const float* __restrict__ state,
                                                     const float* __restrict__ A,
                                                     float* __restrict__ out_state) {
  int idx = blockIdx.x * 256 + threadIdx.x;
  int h = idx >> 14;
  int de = idx & 16383;
  float B = A[(size_t)h * SQLEN + SQLEN - 1];
  float s = __expf(B) * state[idx];
#pragma unroll
  for (int c = 0; c < 8; c++) s += P[(size_t)(h * 8 + c) * 16384 + de];
  out_state[idx] = s;
}

extern "C" void kernel_launch(void* const* d_in, const int* in_sizes, int n_in,
                              void* d_out, int out_size, void* d_ws, size_t ws_size,
                              hipStream_t stream) {
  const float* x = (const float*)d_in[0];
  const float* state = (const float*)d_in[1];
  const float* W_qkv = (const float*)d_in[2];
  const float* W_alpha = (const float*)d_in[3];
  const float* b_alpha = (const float*)d_in[4];
  const float* alpha_base = (const float*)d_in[5];
  const float* gn_w = (const float*)d_in[6];
  const float* gn_b = (const float*)d_in[7];
  const float* W_out = (const float*)d_in[8];
  const float* W_gate = (const float*)d_in[9];
  const int* offset = (const int*)d_in[10];

  float* ws = (float*)d_ws;
  // fp32 regions (float offsets):
  float* qkv = ws;                    // [0,12582912) alive gemm1 -> xpos
  float* P   = ws + 4194304;          // overlay (qkv dead after xpos)
  float* rn  = ws + 29360128;         // [29360128,33554432)
  float* araw = ws + 33554432;
  float* Acum = ws + 33587200;

  // bf16 overlays (ushort):
  unsigned short* xb    = (unsigned short*)(ws + 12582912); // dead after qkv gemm
  unsigned short* Wqkvb = (unsigned short*)(ws + 16777216); // dead after qkv gemm
  unsigned short* qb    = (unsigned short*)(ws + 12582912);
  unsigned short* kb    = (unsigned short*)(ws + 14680064);
  unsigned short* vb    = (unsigned short*)(ws + 16777216);
  unsigned short* kT_s  = (unsigned short*)(ws + 18874368);
  unsigned short* vT_b  = (unsigned short*)(ws + 20971520);
  unsigned short* stT_b = (unsigned short*)(ws + 23068672);
  unsigned short* rnb   = (unsigned short*)(ws + 25165824); // old ret region (free)
  // phase 2 overlays (safe: written after their underlying readers finish)
  unsigned short* Wgateb = (unsigned short*)(ws + 14680064); // over kb, after retention
  unsigned short* Woutb  = (unsigned short*)(ws + 16777216); // over vb, after transpose
  unsigned short* Hb     = (unsigned short*)(ws + 18874368); // over kT_s, after state_gemm

  float* out = (float*)d_out;
  float* out_state = out + 4194304;

  dim3 blk(256);
  // merged x + W_qkv fp32->bf16 conversion (one launch instead of two)
  f2b2_kernel<<<dim3(16384), blk, 0, stream>>>((const float4*)x, (ushort4*)xb,
                                               (const float4*)W_qkv, (ushort4*)Wqkvb, 4096);
  gemm_bf16_nt<<<dim3(48, 16), blk, 0, stream>>>(xb, Wqkvb, qkv, 2048, 6144, 2048);

  alpha_kernel<<<dim3(512), blk, 0, stream>>>(x, W_alpha, b_alpha, alpha_base, araw);
  cumsum_kernel<<<dim3(16), blk, 0, stream>>>(araw, Acum);
  xpos_kernel<<<dim3(8192), blk, 0, stream>>>(qkv, araw, offset, qb, kb, vb);
  transpose_kv_kernel<<<dim3(32, 2, 32), blk, 0, stream>>>(kb, vb, Acum, kT_s, vT_b);
  transpose_state_kernel<<<dim3(2, 2, 16), blk, 0, stream>>>(state, stT_b);

  retention_mfma<<<dim3(16, 32), blk, 0, stream>>>(qb, kb, vT_b, stT_b, Acum,
                                                   gn_w, gn_b, rn, rnb);
  state_gemm<<<dim3(8, 16), blk, 0, stream>>>(kT_s, vT_b, P);
  state_combine<<<dim3(1024), blk, 0, stream>>>(P, state, Acum, out_state);

  f2b2_kernel<<<dim3(8192), blk, 0, stream>>>((const float4*)W_gate, (ushort4*)Wgateb,
                                              (const float4*)W_out, (ushort4*)Woutb, 4096);
  gemm_swish_nt<<<dim3(16, 16), blk, 0, stream>>>(rnb, Wgateb, rn, Hb, 2048, 2048, 2048);
  gemm_bf16_nt<<<dim3(16, 16), blk, 0, stream>>>(Hb, Woutb, out, 2048, 2048, 2048);
}

// Round 2
// 428.366 us; speedup vs baseline: 1.0155x; 1.0155x over previous
//
#include <hip/hip_runtime.h>
#include <cstddef>

#define SQLEN 2048
#define DMODEL 2048
#define NHEADS 16
#define DHEAD 128

typedef __attribute__((ext_vector_type(8))) short bf16x8;
typedef __attribute__((ext_vector_type(4))) float floatx4;

__device__ __forceinline__ unsigned short f2bf(float f) {
  union { float f; unsigned u; } c; c.f = f;
  unsigned u = c.u;
  unsigned r = u + 0x7fffu + ((u >> 16) & 1u);
  return (unsigned short)(r >> 16);
}
__device__ __forceinline__ float bf2f(unsigned short s) {
  union { unsigned u; float f; } c; c.u = ((unsigned)s) << 16;
  return c.f;
}

// ---------------- fp32 -> bf16 convert (vectorized) -------------------------
__global__ __launch_bounds__(256) void f2b_kernel(const float4* __restrict__ in,
                                                  ushort4* __restrict__ out) {
  int i = blockIdx.x * 256 + threadIdx.x;
  float4 v = in[i];
  ushort4 o;
  o.x = f2bf(v.x); o.y = f2bf(v.y); o.z = f2bf(v.z); o.w = f2bf(v.w);
  out[i] = o;
}

// two-array variant (two tensors in one launch)
__global__ __launch_bounds__(256) void f2b2_kernel(const float4* __restrict__ in0,
                                                   ushort4* __restrict__ out0,
                                                   const float4* __restrict__ in1,
                                                   ushort4* __restrict__ out1,
                                                   int half_blocks) {
  int b = blockIdx.x;
  const float4* in = (b < half_blocks) ? in0 : in1;
  ushort4* out = (b < half_blocks) ? out0 : out1;
  int i = (b < half_blocks ? b : b - half_blocks) * 256 + threadIdx.x;
  float4 v = in[i];
  ushort4 o;
  o.x = f2bf(v.x); o.y = f2bf(v.y); o.z = f2bf(v.z); o.w = f2bf(v.w);
  out[i] = o;
}

// =================== 256x256 8-phase bf16 GEMM (C = A @ B^T) ================
// 512 thr / 8 waves (2M x 4N). LDS 128KiB: [buf][A,B][half 128x64] bf16.
// Per phase: one 128x128 C-quadrant (16 MFMA/wave) + 1 half-tile stage.
// Counted vmcnt(4) inside phases 4/8 before the mid-phase barrier.
// LDS read swizzle: 16B-slot ^= (row&7); source pre-swizzled to match.
#define GLD(srcp, dstp) __builtin_amdgcn_global_load_lds( \
    (const __attribute__((address_space(1))) unsigned int*)(srcp), \
    (__attribute__((address_space(3))) unsigned int*)(dstp), 16, 0, 0)

__global__ __launch_bounds__(512, 2) void gemm256_nt(const unsigned short* __restrict__ A,
                                                     const unsigned short* __restrict__ B,
                                                     float* __restrict__ C,
                                                     int M, int N, int K) {
  __shared__ __align__(16) unsigned short lds[65536];  // 128 KiB
  int tid = threadIdx.x;
  int wave = tid >> 6, lane = tid & 63;
  int wm = wave >> 2, wn = wave & 3;            // 2 x 4 wave grid
  int quad = lane >> 4, m16 = lane & 15;
  int sw = m16 & 7;

  // XCD-aware bijective swizzle (nwg % 8 == 0 guaranteed by launch config)
  int nTN = gridDim.x;
  int lin = blockIdx.y * nTN + blockIdx.x;
  int nwg = gridDim.x * gridDim.y;
  int swzb = (nwg & 7) == 0 ? ((lin & 7) * (nwg >> 3) + (lin >> 3)) : lin;
  int row0 = (swzb / nTN) * 256, col0 = (swzb % nTN) * 256;

  const int nkt = K >> 6;    // K-tiles of 64
  const int nit = K >> 7;    // loop iters (2 tiles each)

  // staging per-thread geometry: row = tid/8 (+64 for round 1), 16B slot = tid&7
  int srow = tid >> 3;
  int scol8 = (((tid & 7) ^ ((tid >> 3) & 7)) * 8);  // pre-swizzled global col

  floatx4 acc[2][2][4][2];
#pragma unroll
  for (int a = 0; a < 2; a++)
#pragma unroll
    for (int b = 0; b < 2; b++)
#pragma unroll
      for (int c = 0; c < 4; c++)
#pragma unroll
        for (int d = 0; d < 2; d++) acc[a][b][c][d] = (floatx4){0.f, 0.f, 0.f, 0.f};

#define STAGE(t_, ab_, h_) do { \
    int t2_ = (t_); if (t2_ >= nkt) t2_ -= nkt; \
    const unsigned short* gp_ = (ab_) ? B : A; \
    int rb_ = ((ab_) ? col0 : row0) + (h_) * 128 + srow; \
    int kk_ = t2_ * 64 + scol8; \
    unsigned bs_ = ((unsigned)((t_) & 1)) * 32768u + (ab_) * 16384u + (h_) * 8192u; \
    GLD(gp_ + (size_t)rb_ * K + kk_, lds + bs_ + tid * 8); \
    GLD(gp_ + (size_t)(rb_ + 64) * K + kk_, lds + bs_ + 4096 + tid * 8); \
  } while (0)

#define VMW asm volatile("s_waitcnt vmcnt(4)" ::: "memory");

#define PHASE(BUF_, MH_, NH_, STG_, W_) do { \
    bf16x8 paf[2][4], pbf[2][2]; \
    const unsigned short* Ab_ = lds + (BUF_) * 32768 + (MH_) * 8192; \
    const unsigned short* Bb_ = lds + (BUF_) * 32768 + 16384 + (NH_) * 8192; \
    _Pragma("unroll") for (int ks = 0; ks < 2; ks++) { \
      _Pragma("unroll") for (int fi = 0; fi < 4; fi++) \
        paf[ks][fi] = *(const bf16x8*)(Ab_ + (wm * 64 + fi * 16 + m16) * 64 + (((ks * 4 + quad) ^ sw) * 8)); \
      _Pragma("unroll") for (int gj = 0; gj < 2; gj++) \
        pbf[ks][gj] = *(const bf16x8*)(Bb_ + (wn * 32 + gj * 16 + m16) * 64 + (((ks * 4 + quad) ^ sw) * 8)); \
    } \
    STG_; \
    W_ \
    __builtin_amdgcn_s_barrier(); \
    asm volatile("s_waitcnt lgkmcnt(0)" ::: "memory"); \
    __builtin_amdgcn_sched_barrier(0); \
    __builtin_amdgcn_s_setprio(1); \
    _Pragma("unroll") for (int ks = 0; ks < 2; ks++) \
      _Pragma("unroll") for (int fi = 0; fi < 4; fi++) \
        _Pragma("unroll") for (int gj = 0; gj < 2; gj++) \
          acc[MH_][NH_][fi][gj] = __builtin_amdgcn_mfma_f32_16x16x32_bf16( \
              paf[ks][fi], pbf[ks][gj], acc[MH_][NH_][fi][gj], 0, 0, 0); \
    __builtin_amdgcn_s_setprio(0); \
    __builtin_amdgcn_sched_barrier(0); \
    __builtin_amdgcn_s_barrier(); \
  } while (0)

  // prologue: T0 fully + T1.B0 + T1.A0  (stream pos matches steady state)
  STAGE(0, 1, 0);
  STAGE(0, 0, 0);
  STAGE(0, 0, 1);
  STAGE(0, 1, 1);
  STAGE(1, 1, 0);
  STAGE(1, 0, 0);
  asm volatile("s_waitcnt vmcnt(4)" ::: "memory");  // T0 landed (own wave)
  __builtin_amdgcn_s_barrier();                     // -> landed globally

  for (int it = 0; it < nit; ++it) {
    int T = it * 2;
    PHASE(0, 0, 0, STAGE(T + 1, 0, 1), );    // p1: reads T.A0,T.B0
    PHASE(0, 1, 0, STAGE(T + 1, 1, 1), );    // p2: reads T.A1,T.B0
    PHASE(0, 0, 1, STAGE(T + 2, 1, 0), );    // p3: reads T.A0,T.B1
    PHASE(0, 1, 1, STAGE(T + 2, 0, 0), VMW); // p4: reads T.A1,T.B1; wait->barrier
    PHASE(1, 0, 0, STAGE(T + 2, 0, 1), );    // p5: tile T+1
    PHASE(1, 1, 0, STAGE(T + 2, 1, 1), );    // p6
    PHASE(1, 0, 1, STAGE(T + 3, 1, 0), );    // p7
    PHASE(1, 1, 1, STAGE(T + 3, 0, 0), VMW); // p8
  }

#pragma unroll
  for (int mh = 0; mh < 2; mh++)
#pragma unroll
    for (int nh = 0; nh < 2; nh++)
#pragma unroll
      for (int fi = 0; fi < 4; fi++)
#pragma unroll
        for (int gj = 0; gj < 2; gj++) {
          int rr = row0 + mh * 128 + wm * 64 + fi * 16 + quad * 4;
          int cc = col0 + nh * 128 + wn * 32 + gj * 16 + m16;
#pragma unroll
          for (int r = 0; r < 4; r++)
            C[(size_t)(rr + r) * N + cc] = acc[mh][nh][fi][gj][r];
        }
#undef PHASE
#undef VMW
#undef STAGE
}

// ---------------- bf16 MFMA GEMM: C[M,N] = A[M,K] @ B[N,K]^T ----------------
__global__ __launch_bounds__(256) void gemm_bf16_nt(const unsigned short* __restrict__ A,
                                                    const unsigned short* __restrict__ B,
                                                    float* __restrict__ C,
                                                    int M, int N, int K) {
  __shared__ __align__(16) unsigned short As[128 * 32];
  __shared__ __align__(16) unsigned short Bs[128 * 32];
  int tid = threadIdx.x;
  int wave = tid >> 6;
  int lane = tid & 63;
  int wm = wave >> 1, wn = wave & 1;
  int quad = lane >> 4, m16 = lane & 15;
  int row0 = blockIdx.y * 128, col0 = blockIdx.x * 128;

  floatx4 acc[4][4];
#pragma unroll
  for (int i = 0; i < 4; i++)
#pragma unroll
    for (int j = 0; j < 4; j++) acc[i][j] = (floatx4){0.f, 0.f, 0.f, 0.f};

  int c0 = tid, c1 = tid + 256;
  int r0c = c0 >> 2, q0c = (c0 & 3) * 8;
  int r1c = c1 >> 2, q1c = (c1 & 3) * 8;

  const size_t sK = (size_t)K;
  for (int k0 = 0; k0 < K; k0 += 32) {
    __builtin_amdgcn_global_load_lds(
        (const __attribute__((address_space(1))) unsigned int*)(A + (size_t)(row0 + r0c) * sK + k0 + q0c),
        (__attribute__((address_space(3))) unsigned int*)(As + c0 * 8), 16, 0, 0);
    __builtin_amdgcn_global_load_lds(
        (const __attribute__((address_space(1))) unsigned int*)(A + (size_t)(row0 + r1c) * sK + k0 + q1c),
        (__attribute__((address_space(3))) unsigned int*)(As + c1 * 8), 16, 0, 0);
    __builtin_amdgcn_global_load_lds(
        (const __attribute__((address_space(1))) unsigned int*)(B + (size_t)(col0 + r0c) * sK + k0 + q0c),
        (__attribute__((address_space(3))) unsigned int*)(Bs + c0 * 8), 16, 0, 0);
    __builtin_amdgcn_global_load_lds(
        (const __attribute__((address_space(1))) unsigned int*)(B + (size_t)(col0 + r1c) * sK + k0 + q1c),
        (__attribute__((address_space(3))) unsigned int*)(Bs + c1 * 8), 16, 0, 0);
    __syncthreads();

    bf16x8 af[4], bfr[4];
#pragma unroll
    for (int i = 0; i < 4; i++)
      af[i] = *(const bf16x8*)(As + (wm * 64 + i * 16 + m16) * 32 + quad * 8);
#pragma unroll
    for (int j = 0; j < 4; j++)
      bfr[j] = *(const bf16x8*)(Bs + (wn * 64 + j * 16 + m16) * 32 + quad * 8);
#pragma unroll
    for (int i = 0; i < 4; i++)
#pragma unroll
      for (int j = 0; j < 4; j++)
        acc[i][j] = __builtin_amdgcn_mfma_f32_16x16x32_bf16(af[i], bfr[j], acc[i][j], 0, 0, 0);
    __syncthreads();
  }

#pragma unroll
  for (int i = 0; i < 4; i++) {
#pragma unroll
    for (int j = 0; j < 4; j++) {
      int rr = row0 + wm * 64 + i * 16 + quad * 4;
      int cc = col0 + wn * 64 + j * 16 + m16;
#pragma unroll
      for (int r = 0; r < 4; r++)
        C[(size_t)(rr + r) * N + cc] = acc[i][j][r];
    }
  }
}

// ------- gate GEMM with fused swish*rn epilogue, bf16 output ---------------
__global__ __launch_bounds__(256) void gemm_swish_nt(const unsigned short* __restrict__ A,
                                                     const unsigned short* __restrict__ B,
                                                     const float* __restrict__ rn,
                                                     unsigned short* __restrict__ Hb,
                                                     int M, int N, int K) {
  __shared__ __align__(16) unsigned short As[128 * 32];
  __shared__ __align__(16) unsigned short Bs[128 * 32];
  int tid = threadIdx.x;
  int wave = tid >> 6;
  int lane = tid & 63;
  int wm = wave >> 1, wn = wave & 1;
  int quad = lane >> 4, m16 = lane & 15;
  int row0 = blockIdx.y * 128, col0 = blockIdx.x * 128;

  floatx4 acc[4][4];
#pragma unroll
  for (int i = 0; i < 4; i++)
#pragma unroll
    for (int j = 0; j < 4; j++) acc[i][j] = (floatx4){0.f, 0.f, 0.f, 0.f};

  int c0 = tid, c1 = tid + 256;
  int r0c = c0 >> 2, q0c = (c0 & 3) * 8;
  int r1c = c1 >> 2, q1c = (c1 & 3) * 8;

  const size_t sK = (size_t)K;
  for (int k0 = 0; k0 < K; k0 += 32) {
    __builtin_amdgcn_global_load_lds(
        (const __attribute__((address_space(1))) unsigned int*)(A + (size_t)(row0 + r0c) * sK + k0 + q0c),
        (__attribute__((address_space(3))) unsigned int*)(As + c0 * 8), 16, 0, 0);
    __builtin_amdgcn_global_load_lds(
        (const __attribute__((address_space(1))) unsigned int*)(A + (size_t)(row0 + r1c) * sK + k0 + q1c),
        (__attribute__((address_space(3))) unsigned int*)(As + c1 * 8), 16, 0, 0);
    __builtin_amdgcn_global_load_lds(
        (const __attribute__((address_space(1))) unsigned int*)(B + (size_t)(col0 + r0c) * sK + k0 + q0c),
        (__attribute__((address_space(3))) unsigned int*)(Bs + c0 * 8), 16, 0, 0);
    __builtin_amdgcn_global_load_lds(
        (const __attribute__((address_space(1))) unsigned int*)(B + (size_t)(col0 + r1c) * sK + k0 + q1c),
        (__attribute__((address_space(3))) unsigned int*)(Bs + c1 * 8), 16, 0, 0);
    __syncthreads();

    bf16x8 af[4], bfr[4];
#pragma unroll
    for (int i = 0; i < 4; i++)
      af[i] = *(const bf16x8*)(As + (wm * 64 + i * 16 + m16) * 32 + quad * 8);
#pragma unroll
    for (int j = 0; j < 4; j++)
      bfr[j] = *(const bf16x8*)(Bs + (wn * 64 + j * 16 + m16) * 32 + quad * 8);
#pragma unroll
    for (int i = 0; i < 4; i++)
#pragma unroll
      for (int j = 0; j < 4; j++)
        acc[i][j] = __builtin_amdgcn_mfma_f32_16x16x32_bf16(af[i], bfr[j], acc[i][j], 0, 0, 0);
    __syncthreads();
  }

#pragma unroll
  for (int i = 0; i < 4; i++) {
#pragma unroll
    for (int j = 0; j < 4; j++) {
      int rr = row0 + wm * 64 + i * 16 + quad * 4;
      int cc = col0 + wn * 64 + j * 16 + m16;
#pragma unroll
      for (int r = 0; r < 4; r++) {
        float g = acc[i][j][r];
        float rv = rn[(size_t)(rr + r) * N + cc];
        float hh = g / (1.f + __expf(-g)) * rv;
        Hb[(size_t)(rr + r) * N + cc] = f2bf(hh);
      }
    }
  }
}

// ---------------- alpha: block = 4 t-rows staged in LDS, loop 16 heads ------
__global__ __launch_bounds__(256) void alpha_kernel(const float* __restrict__ x,
                                                    const float* __restrict__ W_alpha,
                                                    const float* __restrict__ b_alpha,
                                                    const float* __restrict__ alpha_base,
                                                    float* __restrict__ a_raw) {
  __shared__ float xs[4][2048];
  int tid = threadIdx.x;
  int t0 = blockIdx.x * 4;
#pragma unroll
  for (int p = 0; p < 8; p++) {
    int idx = tid + p * 256;
    int row = idx >> 9, c4 = idx & 511;
    *(float4*)&xs[row][c4 * 4] = *(const float4*)(x + (size_t)(t0 + row) * DMODEL + c4 * 4);
  }
  __syncthreads();
  int w = tid >> 6, lane = tid & 63;
  int t = t0 + w;
#pragma unroll
  for (int h = 0; h < NHEADS; h++) {
    const float4* wr = (const float4*)(W_alpha + (size_t)h * DMODEL);
    float s = 0.f;
#pragma unroll
    for (int i = lane; i < 512; i += 64) {
      float4 a = *(const float4*)&xs[w][i * 4];
      float4 b = wr[i];
      s += a.x * b.x + a.y * b.y + a.z * b.z + a.w * b.w;
    }
#pragma unroll
    for (int off = 32; off > 0; off >>= 1) s += __shfl_down(s, off);
    if (lane == 0) {
      float sig = 1.f / (1.f + __expf(-(s + b_alpha[h])));
      a_raw[(size_t)h * SQLEN + t] = alpha_base[h] * 8.f * sig;
    }
  }
}

// ---------------- cumsum ----------------------------------------------------
__global__ __launch_bounds__(256) void cumsum_kernel(const float* __restrict__ a_raw,
                                                     float* __restrict__ A) {
  int h = blockIdx.x;
  __shared__ float part[256];
  int tid = threadIdx.x;
  float v[8];
  float s = 0.f;
#pragma unroll
  for (int i = 0; i < 8; i++) {
    v[i] = a_raw[(size_t)h * SQLEN + tid * 8 + i];
    s += v[i];
  }
  part[tid] = s;
  __syncthreads();
  for (int off = 1; off < 256; off <<= 1) {
    float tmp = (tid >= off) ? part[tid - off] : 0.f;
    __syncthreads();
    part[tid] += tmp;
    __syncthreads();
  }
  float run = (tid > 0) ? part[tid - 1] : 0.f;
#pragma unroll
  for (int i = 0; i < 8; i++) {
    run += v[i];
    A[(size_t)h * SQLEN + tid * 8 + i] = run;
  }
}

// ---------------- xPos: emit q,k,v directly as bf16 [h][t][d] ---------------
__global__ __launch_bounds__(256) void xpos_kernel(const float* __restrict__ qkv,
                                                   const float* __restrict__ a_raw,
                                                   const int* __restrict__ offset_p,
                                                   unsigned short* __restrict__ qb,
                                                   unsigned short* __restrict__ kb,
                                                   unsigned short* __restrict__ vb) {
  int idx = blockIdx.x * 256 + threadIdx.x;
  int j = idx & 63;
  int t = (idx >> 6) & 2047;
  int h = idx >> 17;
  float pos = (float)(t + offset_p[0]);
  float freq = exp2f(-(float)j * (13.287712379549449f / 64.f));
  float ang = pos * freq;
  float sn = __sinf(ang), cs = __cosf(ang);
  float zeta = (2.f * (float)j + 51.2f) / 179.2f;
  float lzp = __log2f(zeta) * pos * (1.f / 512.f);
  float sc = exp2f(lzp);
  float sci = exp2f(-lzp);
  const float* row = qkv + (size_t)t * (3 * DMODEL);
  int base = h * DHEAD + j;
  float q1 = row[base], q2 = row[base + 64];
  float k1 = row[DMODEL + base], k2 = row[DMODEL + base + 64];
  float v1 = row[2 * DMODEL + base], v2 = row[2 * DMODEL + base + 64];
  size_t o = ((size_t)h * SQLEN + t) * DHEAD + j;
  qb[o] = f2bf((q1 * cs - q2 * sn) * sc);
  qb[o + 64] = f2bf((q2 * cs + q1 * sn) * sc);
  float km = (1.f - __expf(a_raw[(size_t)h * SQLEN + t])) * sci;
  kb[o] = f2bf((k1 * cs - k2 * sn) * km);
  kb[o + 64] = f2bf((k2 * cs + k1 * sn) * km);
  vb[o] = f2bf(v1);
  vb[o + 64] = f2bf(v2);
}

// ------- transpose kb/vb [h][t][d] -> [h][d][t]; k gets exp(B-A[t]) scale ---
__global__ __launch_bounds__(256) void transpose_kv_kernel(const unsigned short* __restrict__ kb,
                                                           const unsigned short* __restrict__ vb,
                                                           const float* __restrict__ A,
                                                           unsigned short* __restrict__ kT,
                                                           unsigned short* __restrict__ vT) {
  __shared__ __align__(16) unsigned short tile[64][72];
  int h = blockIdx.z >> 1, sel = blockIdx.z & 1;
  int t0 = blockIdx.x * 64, d0 = blockIdx.y * 64;
  int tid = threadIdx.x;
  const unsigned short* src = (sel ? vb : kb) + ((size_t)h * SQLEN + t0) * DHEAD + d0;
  unsigned short* dst = (sel ? vT : kT) + (size_t)h * (DHEAD * SQLEN) + (size_t)d0 * SQLEN + t0;
  float B = A[(size_t)h * SQLEN + SQLEN - 1];
#pragma unroll
  for (int p = 0; p < 2; p++) {
    int c = tid + p * 256;
    int r = c >> 3, off = (c & 7) * 8;
    bf16x8 in = *(const bf16x8*)(src + (size_t)r * DHEAD + off);
    if (!sel) {
      float w = __expf(B - A[(size_t)h * SQLEN + t0 + r]);
      bf16x8 o;
#pragma unroll
      for (int j = 0; j < 8; j++) o[j] = (short)f2bf(bf2f((unsigned short)in[j]) * w);
      *(bf16x8*)&tile[r][off] = o;
    } else {
      *(bf16x8*)&tile[r][off] = in;
    }
  }
  __syncthreads();
#pragma unroll
  for (int p = 0; p < 2; p++) {
    int c = tid + p * 256;
    int dr = c >> 3, toff = (c & 7) * 8;
    bf16x8 o;
#pragma unroll
    for (int j = 0; j < 8; j++) o[j] = (short)tile[toff + j][dr];
    *(bf16x8*)(dst + (size_t)dr * SQLEN + toff) = o;
  }
}

// ---------------- transpose state -> stT bf16 [h][e][d] ---------------------
__global__ __launch_bounds__(256) void transpose_state_kernel(const float* __restrict__ st,
                                                              unsigned short* __restrict__ stT) {
  __shared__ float tile[64][65];
  int h = blockIdx.z, d0 = blockIdx.x * 64, e0 = blockIdx.y * 64;
  int tid = threadIdx.x;
  const float* src = st + (size_t)h * 16384 + (size_t)d0 * DHEAD + e0;
#pragma unroll
  for (int p = 0; p < 4; p++) {
    int idx = tid + p * 256;
    int r = idx >> 4, c = (idx & 15) * 4;
    float4 f = *(const float4*)(src + (size_t)r * DHEAD + c);
    tile[r][c] = f.x; tile[r][c + 1] = f.y; tile[r][c + 2] = f.z; tile[r][c + 3] = f.w;
  }
  __syncthreads();
  unsigned short* dst = stT + (size_t)h * 16384 + (size_t)e0 * DHEAD + d0;
#pragma unroll
  for (int p = 0; p < 2; p++) {
    int idx = tid + p * 256;
    int er = idx >> 3, doff = (idx & 7) * 8;
    bf16x8 o;
#pragma unroll
    for (int j = 0; j < 8; j++) o[j] = (short)f2bf(tile[doff + j][er]);
    *(bf16x8*)(dst + (size_t)er * DHEAD + doff) = o;
  }
}

// ---------------- retention v3: fused group-norm epilogue -------------------
__global__ __launch_bounds__(256) void retention_mfma(const unsigned short* __restrict__ qb,
                                                      const unsigned short* __restrict__ kb,
                                                      const unsigned short* __restrict__ vT,
                                                      const unsigned short* __restrict__ stT,
                                                      const float* __restrict__ A,
                                                      const float* __restrict__ gn_w,
                                                      const float* __restrict__ gn_b,
                                                      float* __restrict__ rn,
                                                      unsigned short* __restrict__ rnb) {
  __shared__ __align__(16) unsigned short ks[64 * 128];
  __shared__ __align__(16) unsigned short vs[128 * 64];
  __shared__ __align__(16) unsigned short Ss[64 * 72];
  __shared__ float djs[64];
  int h = blockIdx.x;
  int i0 = blockIdx.y * 64;
  int tid = threadIdx.x;
  int wave = tid >> 6, lane = tid & 63, quad = lane >> 4, m16 = lane & 15;
  const float* Ah = A + (size_t)h * SQLEN;
  float c = Ah[i0];
  int rq = wave * 16 + m16;

  const unsigned short* qh = qb + ((size_t)h * SQLEN + i0 + rq) * DHEAD;
  bf16x8 qf[4];
#pragma unroll
  for (int dc = 0; dc < 4; dc++)
    qf[dc] = *(const bf16x8*)(qh + dc * 32 + quad * 8);
  float ei = __expf(Ah[i0 + rq] - c);

  float wg[8], bg[8];
#pragma unroll
  for (int et = 0; et < 8; et++) {
    int col = h * DHEAD + et * 16 + m16;
    wg[et] = gn_w[col];
    bg[et] = gn_b[col];
  }

  floatx4 acc[8];
#pragma unroll
  for (int et = 0; et < 8; et++) acc[et] = (floatx4){0.f, 0.f, 0.f, 0.f};

  if (c > -87.f) {
    const unsigned short* sp = stT + (size_t)h * 16384;
    float ecr[4];
#pragma unroll
    for (int r = 0; r < 4; r++) ecr[r] = __expf(Ah[i0 + wave * 16 + quad * 4 + r]);
#pragma unroll
    for (int et = 0; et < 8; et++) {
#pragma unroll
      for (int dc = 0; dc < 4; dc++) {
        bf16x8 sf = *(const bf16x8*)(sp + (et * 16 + m16) * DHEAD + dc * 32 + quad * 8);
        acc[et] = __builtin_amdgcn_mfma_f32_16x16x32_bf16(qf[dc], sf, acc[et], 0, 0, 0);
      }
#pragma unroll
      for (int r = 0; r < 4; r++) acc[et][r] *= ecr[r];
    }
  }

  for (int j0 = 0; j0 <= i0; j0 += 64) {
    if (c - Ah[j0 + 63] < -87.f) continue;
    __syncthreads();
    const unsigned short* kh = kb + ((size_t)h * SQLEN + j0) * DHEAD;
    const unsigned short* vh = vT + (size_t)h * (DHEAD * SQLEN) + j0;
#pragma unroll
    for (int p = 0; p < 4; p++) {
      int cch = tid + p * 256;
      int r = cch >> 4, kp = (cch & 15) ^ (r & 7);
      __builtin_amdgcn_global_load_lds(
          (const __attribute__((address_space(1))) unsigned int*)(kh + (size_t)r * DHEAD + kp * 8),
          (__attribute__((address_space(3))) unsigned int*)(ks + cch * 8), 16, 0, 0);
      int e = cch >> 3, tp = (cch & 7) ^ (e & 7);
      __builtin_amdgcn_global_load_lds(
          (const __attribute__((address_space(1))) unsigned int*)(vh + (size_t)e * SQLEN + tp * 8),
          (__attribute__((address_space(3))) unsigned int*)(vs + cch * 8), 16, 0, 0);
    }
    if (tid < 64) djs[tid] = __expf(c - Ah[j0 + tid]);
    __syncthreads();

    bool diag = (j0 == i0);
#pragma unroll
    for (int jt = 0; jt < 4; jt++) {
      floatx4 s = (floatx4){0.f, 0.f, 0.f, 0.f};
#pragma unroll
      for (int dc = 0; dc < 4; dc++) {
        int rk = jt * 16 + m16;
        bf16x8 kf = *(const bf16x8*)(ks + rk * 128 + (((dc * 4 + quad) ^ (rk & 7)) * 8));
        s = __builtin_amdgcn_mfma_f32_16x16x32_bf16(kf, qf[dc], s, 0, 0, 0);
      }
      int jb = jt * 16 + quad * 4;
      float4 dj4 = *(const float4*)&djs[jb];
      ushort4 pk;
      pk.x = f2bf((diag && (jb + 0 > rq)) ? 0.f : s[0] * ei * dj4.x);
      pk.y = f2bf((diag && (jb + 1 > rq)) ? 0.f : s[1] * ei * dj4.y);
      pk.z = f2bf((diag && (jb + 2 > rq)) ? 0.f : s[2] * ei * dj4.z);
      pk.w = f2bf((diag && (jb + 3 > rq)) ? 0.f : s[3] * ei * dj4.w);
      *(ushort4*)(Ss + rq * 72 + jb) = pk;
    }

    bf16x8 sfr[2];
#pragma unroll
    for (int kc = 0; kc < 2; kc++)
      sfr[kc] = *(const bf16x8*)(Ss + rq * 72 + kc * 32 + quad * 8);
#pragma unroll
    for (int et = 0; et < 8; et++) {
#pragma unroll
      for (int kc = 0; kc < 2; kc++) {
        int e = et * 16 + m16;
        bf16x8 vf = *(const bf16x8*)(vs + e * 64 + (((kc * 4 + quad) ^ (e & 7)) * 8));
        acc[et] = __builtin_amdgcn_mfma_f32_16x16x32_bf16(sfr[kc], vf, acc[et], 0, 0, 0);
      }
    }
  }

#pragma unroll
  for (int r = 0; r < 4; r++) {
    float s = 0.f, ss = 0.f;
#pragma unroll
    for (int et = 0; et < 8; et++) {
      float v = acc[et][r];
      s += v; ss += v * v;
    }
#pragma unroll
    for (int off = 8; off > 0; off >>= 1) {
      s += __shfl_xor(s, off);
      ss += __shfl_xor(ss, off);
    }
    float mu = s * (1.f / 128.f);
    float var = ss * (1.f / 128.f) - mu * mu;
    float inv = rsqrtf(var + 1e-5f);
    int row = i0 + wave * 16 + quad * 4 + r;
    size_t o = (size_t)row * DMODEL + h * DHEAD;
#pragma unroll
    for (int et = 0; et < 8; et++) {
      float rv = (acc[et][r] - mu) * inv * wg[et] + bg[et];
      rn[o + et * 16 + m16] = rv;
      rnb[o + et * 16 + m16] = f2bf(rv);
    }
  }
}

// -------- new_state GEMM: P[h,chunk] = kT_s[:,krange] @ vT[:,krange]^T ------
__global__ __launch_bounds__(256) void state_gemm(const unsigned short* __restrict__ kT,
                                                  const unsigned short* __restrict__ vT,
                                                  float* __restrict__ P) {
  __shared__ __align__(16) unsigned short As[128 * 32];
  __shared__ __align__(16) unsigned short Bs[128 * 32];
  int chunk = blockIdx.x, h = blockIdx.y;
  int tid = threadIdx.x;
  int wave = tid >> 6, lane = tid & 63;
  int wm = wave >> 1, wn = wave & 1;
  int quad = lane >> 4, m16 = lane & 15;
  const unsigned short* Ab = kT + (size_t)h * (DHEAD * SQLEN);
  const unsigned short* Bb = vT + (size_t)h * (DHEAD * SQLEN);

  floatx4 acc[4][4];
#pragma unroll
  for (int i = 0; i < 4; i++)
#pragma unroll
    for (int j = 0; j < 4; j++) acc[i][j] = (floatx4){0.f, 0.f, 0.f, 0.f};

  int c0 = tid, c1 = tid + 256;
  int r0c = c0 >> 2, q0c = (c0 & 3) * 8;
  int r1c = c1 >> 2, q1c = (c1 & 3) * 8;

  for (int k0 = chunk * 256; k0 < chunk * 256 + 256; k0 += 32) {
    __builtin_amdgcn_global_load_lds(
        (const __attribute__((address_space(1))) unsigned int*)(Ab + (size_t)r0c * SQLEN + k0 + q0c),
        (__attribute__((address_space(3))) unsigned int*)(As + c0 * 8), 16, 0, 0);
    __builtin_amdgcn_global_load_lds(
        (const __attribute__((address_space(1))) unsigned int*)(Ab + (size_t)r1c * SQLEN + k0 + q1c),
        (__attribute__((address_space(3))) unsigned int*)(As + c1 * 8), 16, 0, 0);
    __builtin_amdgcn_global_load_lds(
        (const __attribute__((address_space(1))) unsigned int*)(Bb + (size_t)r0c * SQLEN + k0 + q0c),
        (__attribute__((address_space(3))) unsigned int*)(Bs + c0 * 8), 16, 0, 0);
    __builtin_amdgcn_global_load_lds(
        (const __attribute__((address_space(1))) unsigned int*)(Bb + (size_t)r1c * SQLEN + k0 + q1c),
        (__attribute__((address_space(3))) unsigned int*)(Bs + c1 * 8), 16, 0, 0);
    __syncthreads();

    bf16x8 af[4], bfr[4];
#pragma unroll
    for (int i = 0; i < 4; i++)
      af[i] = *(const bf16x8*)(As + (wm * 64 + i * 16 + m16) * 32 + quad * 8);
#pragma unroll
    for (int j = 0; j < 4; j++)
      bfr[j] = *(const bf16x8*)(Bs + (wn * 64 + j * 16 + m16) * 32 + quad * 8);
#pragma unroll
    for (int i = 0; i < 4; i++)
#pragma unroll
      for (int j = 0; j < 4; j++)
        acc[i][j] = __builtin_amdgcn_mfma_f32_16x16x32_bf16(af[i], bfr[j], acc[i][j], 0, 0, 0);
    __syncthreads();
  }

  float* Pp = P + (size_t)(h * 8 + chunk) * 16384;
#pragma unroll
  for (int i = 0; i < 4; i++)
#pragma unroll
    for (int j = 0; j < 4; j++) {
      int rr = wm * 64 + i * 16 + quad * 4;
      int cc = wn * 64 + j * 16 + m16;
#pragma unroll
      for (int r = 0; r < 4; r++)
        Pp[(size_t)(rr + r) * DHEAD + cc] = acc[i][j][r];
    }
}

__global__ __launch_bounds__(256) void state_combine(const float* __restrict__ P,
                                                     const float* __restrict__ state,
                                                     const float* __restrict__ A,
                                                     float* __restrict__ out_state) {
  int idx = blockIdx.x * 256 + threadIdx.x;
  int h = idx >> 14;
  int de = idx & 16383;
  float B = A[(size_t)h * SQLEN + SQLEN - 1];
  float s = __expf(B) * state[idx];
#pragma unroll
  for (int c = 0; c < 8; c++) s += P[(size_t)(h * 8 + c) * 16384 + de];
  out_state[idx] = s;
}

extern "C" void kernel_launch(void* const* d_in, const int* in_sizes, int n_in,
                              void* d_out, int out_size, void* d_ws, size_t ws_size,
                              hipStream_t stream) {
  const float* x = (const float*)d_in[0];
  const float* state = (const float*)d_in[1];
  const float* W_qkv = (const float*)d_in[2];
  const float* W_alpha = (const float*)d_in[3];
  const float* b_alpha = (const float*)d_in[4];
  const float* alpha_base = (const float*)d_in[5];
  const float* gn_w = (const float*)d_in[6];
  const float* gn_b = (const float*)d_in[7];
  const float* W_out = (const float*)d_in[8];
  const float* W_gate = (const float*)d_in[9];
  const int* offset = (const int*)d_in[10];

  float* ws = (float*)d_ws;
  float* qkv = ws;
  float* P   = ws + 4194304;
  float* rn  = ws + 29360128;
  float* araw = ws + 33554432;
  float* Acum = ws + 33587200;

  unsigned short* xb    = (unsigned short*)(ws + 12582912);
  unsigned short* Wqkvb = (unsigned short*)(ws + 16777216);
  unsigned short* qb    = (unsigned short*)(ws + 12582912);
  unsigned short* kb    = (unsigned short*)(ws + 14680064);
  unsigned short* vb    = (unsigned short*)(ws + 16777216);
  unsigned short* kT_s  = (unsigned short*)(ws + 18874368);
  unsigned short* vT_b  = (unsigned short*)(ws + 20971520);
  unsigned short* stT_b = (unsigned short*)(ws + 23068672);
  unsigned short* rnb   = (unsigned short*)(ws + 25165824);
  unsigned short* Wgateb = (unsigned short*)(ws + 14680064);
  unsigned short* Woutb  = (unsigned short*)(ws + 16777216);
  unsigned short* Hb     = (unsigned short*)(ws + 18874368);

  float* out = (float*)d_out;
  float* out_state = out + 4194304;

  dim3 blk(256);
  f2b2_kernel<<<dim3(16384), blk, 0, stream>>>((const float4*)x, (ushort4*)xb,
                                               (const float4*)W_qkv, (ushort4*)Wqkvb, 4096);
  // qkv GEMM: 256x256 8-phase pipelined kernel (512 threads, grid 24x8 = 192 wg)
  gemm256_nt<<<dim3(24, 8), dim3(512), 0, stream>>>(xb, Wqkvb, qkv, 2048, 6144, 2048);

  alpha_kernel<<<dim3(512), blk, 0, stream>>>(x, W_alpha, b_alpha, alpha_base, araw);
  cumsum_kernel<<<dim3(16), blk, 0, stream>>>(araw, Acum);
  xpos_kernel<<<dim3(8192), blk, 0, stream>>>(qkv, araw, offset, qb, kb, vb);
  transpose_kv_kernel<<<dim3(32, 2, 32), blk, 0, stream>>>(kb, vb, Acum, kT_s, vT_b);
  transpose_state_kernel<<<dim3(2, 2, 16), blk, 0, stream>>>(state, stT_b);

  retention_mfma<<<dim3(16, 32), blk, 0, stream>>>(qb, kb, vT_b, stT_b, Acum,
                                                   gn_w, gn_b, rn, rnb);
  state_gemm<<<dim3(8, 16), blk, 0, stream>>>(kT_s, vT_b, P);
  state_combine<<<dim3(1024), blk, 0, stream>>>(P, state, Acum, out_state);

  f2b2_kernel<<<dim3(8192), blk, 0, stream>>>((const float4*)W_gate, (ushort4*)Wgateb,
                                              (const float4*)W_out, (ushort4*)Woutb, 4096);
  gemm_swish_nt<<<dim3(16, 16), blk, 0, stream>>>(rnb, Wgateb, rn, Hb, 2048, 2048, 2048);
  gemm_bf16_nt<<<dim3(16, 16), blk, 0, stream>>>(Hb, Woutb, out, 2048, 2048, 2048);
}

// Round 3
// 419.105 us; speedup vs baseline: 1.0379x; 1.0221x over previous
//
#include <hip/hip_runtime.h>
#include <cstddef>

#define SQLEN 2048
#define DMODEL 2048
#define NHEADS 16
#define DHEAD 128

typedef __attribute__((ext_vector_type(8))) short bf16x8;
typedef __attribute__((ext_vector_type(4))) float floatx4;

__device__ __forceinline__ unsigned short f2bf(float f) {
  union { float f; unsigned u; } c; c.f = f;
  unsigned u = c.u;
  unsigned r = u + 0x7fffu + ((u >> 16) & 1u);
  return (unsigned short)(r >> 16);
}
__device__ __forceinline__ float bf2f(unsigned short s) {
  union { unsigned u; float f; } c; c.u = ((unsigned)s) << 16;
  return c.f;
}

// ---------------- fp32 -> bf16 convert (vectorized) -------------------------
__global__ __launch_bounds__(256) void f2b_kernel(const float4* __restrict__ in,
                                                  ushort4* __restrict__ out) {
  int i = blockIdx.x * 256 + threadIdx.x;
  float4 v = in[i];
  ushort4 o;
  o.x = f2bf(v.x); o.y = f2bf(v.y); o.z = f2bf(v.z); o.w = f2bf(v.w);
  out[i] = o;
}

// two-array variant (two tensors in one launch)
__global__ __launch_bounds__(256) void f2b2_kernel(const float4* __restrict__ in0,
                                                   ushort4* __restrict__ out0,
                                                   const float4* __restrict__ in1,
                                                   ushort4* __restrict__ out1,
                                                   int half_blocks) {
  int b = blockIdx.x;
  const float4* in = (b < half_blocks) ? in0 : in1;
  ushort4* out = (b < half_blocks) ? out0 : out1;
  int i = (b < half_blocks ? b : b - half_blocks) * 256 + threadIdx.x;
  float4 v = in[i];
  ushort4 o;
  o.x = f2bf(v.x); o.y = f2bf(v.y); o.z = f2bf(v.z); o.w = f2bf(v.w);
  out[i] = o;
}

// =================== 256x256 8-phase bf16 GEMM (C = A @ B^T) ================
// 512 thr / 8 waves (2M x 4N). LDS 128KiB: [buf][A,B][half 128x64] bf16.
// v2: register-held fragments across the 4 phases of a buffer pass:
//   p1: read A0+B0 -> Q(0,0); p2: read A1 -> Q(1,0); p3: read B1 -> Q(0,1);
//   p4: no ds reads -> Q(1,1).   24 ds_read_b128/wave/pass (was 48).
// Counted vmcnt(4) inside phases 4/8 before the mid-phase barrier.
// LDS read swizzle: 16B-slot ^= (row&7); source pre-swizzled to match.
#define GLD(srcp, dstp) __builtin_amdgcn_global_load_lds( \
    (const __attribute__((address_space(1))) unsigned int*)(srcp), \
    (__attribute__((address_space(3))) unsigned int*)(dstp), 16, 0, 0)

__global__ __launch_bounds__(512, 2) void gemm256_nt(const unsigned short* __restrict__ A,
                                                     const unsigned short* __restrict__ B,
                                                     float* __restrict__ C,
                                                     int M, int N, int K) {
  __shared__ __align__(16) unsigned short lds[65536];  // 128 KiB
  int tid = threadIdx.x;
  int wave = tid >> 6, lane = tid & 63;
  int wm = wave >> 2, wn = wave & 3;            // 2 x 4 wave grid
  int quad = lane >> 4, m16 = lane & 15;
  int sw = m16 & 7;

  // XCD-aware bijective swizzle (nwg % 8 == 0 guaranteed by launch config)
  int nTN = gridDim.x;
  int lin = blockIdx.y * nTN + blockIdx.x;
  int nwg = gridDim.x * gridDim.y;
  int swzb = (nwg & 7) == 0 ? ((lin & 7) * (nwg >> 3) + (lin >> 3)) : lin;
  int row0 = (swzb / nTN) * 256, col0 = (swzb % nTN) * 256;

  const int nkt = K >> 6;    // K-tiles of 64
  const int nit = K >> 7;    // loop iters (2 tiles each)

  // staging per-thread geometry: row = tid/8 (+64 for round 1), 16B slot = tid&7
  int srow = tid >> 3;
  int scol8 = (((tid & 7) ^ ((tid >> 3) & 7)) * 8);  // pre-swizzled global col

  bf16x8 a0[2][4], a1[2][4], bb[2][2];
  floatx4 acc[2][2][4][2];
#pragma unroll
  for (int a = 0; a < 2; a++)
#pragma unroll
    for (int b = 0; b < 2; b++)
#pragma unroll
      for (int c = 0; c < 4; c++)
#pragma unroll
        for (int d = 0; d < 2; d++) acc[a][b][c][d] = (floatx4){0.f, 0.f, 0.f, 0.f};

#define STAGE(t_, ab_, h_) do { \
    int t2_ = (t_); if (t2_ >= nkt) t2_ -= nkt; \
    const unsigned short* gp_ = (ab_) ? B : A; \
    int rb_ = ((ab_) ? col0 : row0) + (h_) * 128 + srow; \
    int kk_ = t2_ * 64 + scol8; \
    unsigned bs_ = ((unsigned)((t_) & 1)) * 32768u + (ab_) * 16384u + (h_) * 8192u; \
    GLD(gp_ + (size_t)rb_ * K + kk_, lds + bs_ + tid * 8); \
    GLD(gp_ + (size_t)(rb_ + 64) * K + kk_, lds + bs_ + 4096 + tid * 8); \
  } while (0)

#define VMW asm volatile("s_waitcnt vmcnt(4)" ::: "memory");

#define RDA(dst_, BUF_, MH_) do { \
    const unsigned short* Ab_ = lds + (BUF_) * 32768 + (MH_) * 8192; \
    _Pragma("unroll") for (int ks = 0; ks < 2; ks++) \
      _Pragma("unroll") for (int fi = 0; fi < 4; fi++) \
        dst_[ks][fi] = *(const bf16x8*)(Ab_ + (wm * 64 + fi * 16 + m16) * 64 + (((ks * 4 + quad) ^ sw) * 8)); \
  } while (0)

#define RDB(BUF_, NH_) do { \
    const unsigned short* Bb_ = lds + (BUF_) * 32768 + 16384 + (NH_) * 8192; \
    _Pragma("unroll") for (int ks = 0; ks < 2; ks++) \
      _Pragma("unroll") for (int gj = 0; gj < 2; gj++) \
        bb[ks][gj] = *(const bf16x8*)(Bb_ + (wn * 32 + gj * 16 + m16) * 64 + (((ks * 4 + quad) ^ sw) * 8)); \
  } while (0)

#define MM(A_, MH_, NH_) \
    _Pragma("unroll") for (int ks = 0; ks < 2; ks++) \
      _Pragma("unroll") for (int fi = 0; fi < 4; fi++) \
        _Pragma("unroll") for (int gj = 0; gj < 2; gj++) \
          acc[MH_][NH_][fi][gj] = __builtin_amdgcn_mfma_f32_16x16x32_bf16( \
              A_[ks][fi], bb[ks][gj], acc[MH_][NH_][fi][gj], 0, 0, 0);

#define PH(RD_, STG_, W_, MM_) do { \
    RD_; \
    STG_; \
    W_ \
    __builtin_amdgcn_s_barrier(); \
    asm volatile("s_waitcnt lgkmcnt(0)" ::: "memory"); \
    __builtin_amdgcn_sched_barrier(0); \
    __builtin_amdgcn_s_setprio(1); \
    MM_ \
    __builtin_amdgcn_s_setprio(0); \
    __builtin_amdgcn_sched_barrier(0); \
    __builtin_amdgcn_s_barrier(); \
  } while (0)

  // prologue: T0 fully + T1.B0 + T1.A0  (stream pos matches steady state)
  STAGE(0, 1, 0);
  STAGE(0, 0, 0);
  STAGE(0, 0, 1);
  STAGE(0, 1, 1);
  STAGE(1, 1, 0);
  STAGE(1, 0, 0);
  asm volatile("s_waitcnt vmcnt(4)" ::: "memory");  // T0 landed (own wave)
  __builtin_amdgcn_s_barrier();                     // -> landed globally

  for (int it = 0; it < nit; ++it) {
    int T = it * 2;
    PH(RDA(a0, 0, 0); RDB(0, 0), STAGE(T + 1, 0, 1), , MM(a0, 0, 0));
    PH(RDA(a1, 0, 1),            STAGE(T + 1, 1, 1), , MM(a1, 1, 0));
    PH(RDB(0, 1),                STAGE(T + 2, 1, 0), , MM(a0, 0, 1));
    PH(,                         STAGE(T + 2, 0, 0), VMW, MM(a1, 1, 1));
    PH(RDA(a0, 1, 0); RDB(1, 0), STAGE(T + 2, 0, 1), , MM(a0, 0, 0));
    PH(RDA(a1, 1, 1),            STAGE(T + 2, 1, 1), , MM(a1, 1, 0));
    PH(RDB(1, 1),                STAGE(T + 3, 1, 0), , MM(a0, 0, 1));
    PH(,                         STAGE(T + 3, 0, 0), VMW, MM(a1, 1, 1));
  }

#pragma unroll
  for (int mh = 0; mh < 2; mh++)
#pragma unroll
    for (int nh = 0; nh < 2; nh++)
#pragma unroll
      for (int fi = 0; fi < 4; fi++)
#pragma unroll
        for (int gj = 0; gj < 2; gj++) {
          int rr = row0 + mh * 128 + wm * 64 + fi * 16 + quad * 4;
          int cc = col0 + nh * 128 + wn * 32 + gj * 16 + m16;
#pragma unroll
          for (int r = 0; r < 4; r++)
            C[(size_t)(rr + r) * N + cc] = acc[mh][nh][fi][gj][r];
        }
#undef PH
#undef MM
#undef RDB
#undef RDA
#undef VMW
#undef STAGE
}

// ---------------- bf16 MFMA GEMM: C[M,N] = A[M,K] @ B[N,K]^T ----------------
__global__ __launch_bounds__(256) void gemm_bf16_nt(const unsigned short* __restrict__ A,
                                                    const unsigned short* __restrict__ B,
                                                    float* __restrict__ C,
                                                    int M, int N, int K) {
  __shared__ __align__(16) unsigned short As[128 * 32];
  __shared__ __align__(16) unsigned short Bs[128 * 32];
  int tid = threadIdx.x;
  int wave = tid >> 6;
  int lane = tid & 63;
  int wm = wave >> 1, wn = wave & 1;
  int quad = lane >> 4, m16 = lane & 15;
  int row0 = blockIdx.y * 128, col0 = blockIdx.x * 128;

  floatx4 acc[4][4];
#pragma unroll
  for (int i = 0; i < 4; i++)
#pragma unroll
    for (int j = 0; j < 4; j++) acc[i][j] = (floatx4){0.f, 0.f, 0.f, 0.f};

  int c0 = tid, c1 = tid + 256;
  int r0c = c0 >> 2, q0c = (c0 & 3) * 8;
  int r1c = c1 >> 2, q1c = (c1 & 3) * 8;

  const size_t sK = (size_t)K;
  for (int k0 = 0; k0 < K; k0 += 32) {
    __builtin_amdgcn_global_load_lds(
        (const __attribute__((address_space(1))) unsigned int*)(A + (size_t)(row0 + r0c) * sK + k0 + q0c),
        (__attribute__((address_space(3))) unsigned int*)(As + c0 * 8), 16, 0, 0);
    __builtin_amdgcn_global_load_lds(
        (const __attribute__((address_space(1))) unsigned int*)(A + (size_t)(row0 + r1c) * sK + k0 + q1c),
        (__attribute__((address_space(3))) unsigned int*)(As + c1 * 8), 16, 0, 0);
    __builtin_amdgcn_global_load_lds(
        (const __attribute__((address_space(1))) unsigned int*)(B + (size_t)(col0 + r0c) * sK + k0 + q0c),
        (__attribute__((address_space(3))) unsigned int*)(Bs + c0 * 8), 16, 0, 0);
    __builtin_amdgcn_global_load_lds(
        (const __attribute__((address_space(1))) unsigned int*)(B + (size_t)(col0 + r1c) * sK + k0 + q1c),
        (__attribute__((address_space(3))) unsigned int*)(Bs + c1 * 8), 16, 0, 0);
    __syncthreads();

    bf16x8 af[4], bfr[4];
#pragma unroll
    for (int i = 0; i < 4; i++)
      af[i] = *(const bf16x8*)(As + (wm * 64 + i * 16 + m16) * 32 + quad * 8);
#pragma unroll
    for (int j = 0; j < 4; j++)
      bfr[j] = *(const bf16x8*)(Bs + (wn * 64 + j * 16 + m16) * 32 + quad * 8);
#pragma unroll
    for (int i = 0; i < 4; i++)
#pragma unroll
      for (int j = 0; j < 4; j++)
        acc[i][j] = __builtin_amdgcn_mfma_f32_16x16x32_bf16(af[i], bfr[j], acc[i][j], 0, 0, 0);
    __syncthreads();
  }

#pragma unroll
  for (int i = 0; i < 4; i++) {
#pragma unroll
    for (int j = 0; j < 4; j++) {
      int rr = row0 + wm * 64 + i * 16 + quad * 4;
      int cc = col0 + wn * 64 + j * 16 + m16;
#pragma unroll
      for (int r = 0; r < 4; r++)
        C[(size_t)(rr + r) * N + cc] = acc[i][j][r];
    }
  }
}

// ------- gate GEMM with fused swish*rn epilogue, bf16 output ---------------
__global__ __launch_bounds__(256) void gemm_swish_nt(const unsigned short* __restrict__ A,
                                                     const unsigned short* __restrict__ B,
                                                     const float* __restrict__ rn,
                                                     unsigned short* __restrict__ Hb,
                                                     int M, int N, int K) {
  __shared__ __align__(16) unsigned short As[128 * 32];
  __shared__ __align__(16) unsigned short Bs[128 * 32];
  int tid = threadIdx.x;
  int wave = tid >> 6;
  int lane = tid & 63;
  int wm = wave >> 1, wn = wave & 1;
  int quad = lane >> 4, m16 = lane & 15;
  int row0 = blockIdx.y * 128, col0 = blockIdx.x * 128;

  floatx4 acc[4][4];
#pragma unroll
  for (int i = 0; i < 4; i++)
#pragma unroll
    for (int j = 0; j < 4; j++) acc[i][j] = (floatx4){0.f, 0.f, 0.f, 0.f};

  int c0 = tid, c1 = tid + 256;
  int r0c = c0 >> 2, q0c = (c0 & 3) * 8;
  int r1c = c1 >> 2, q1c = (c1 & 3) * 8;

  const size_t sK = (size_t)K;
  for (int k0 = 0; k0 < K; k0 += 32) {
    __builtin_amdgcn_global_load_lds(
        (const __attribute__((address_space(1))) unsigned int*)(A + (size_t)(row0 + r0c) * sK + k0 + q0c),
        (__attribute__((address_space(3))) unsigned int*)(As + c0 * 8), 16, 0, 0);
    __builtin_amdgcn_global_load_lds(
        (const __attribute__((address_space(1))) unsigned int*)(A + (size_t)(row0 + r1c) * sK + k0 + q1c),
        (__attribute__((address_space(3))) unsigned int*)(As + c1 * 8), 16, 0, 0);
    __builtin_amdgcn_global_load_lds(
        (const __attribute__((address_space(1))) unsigned int*)(B + (size_t)(col0 + r0c) * sK + k0 + q0c),
        (__attribute__((address_space(3))) unsigned int*)(Bs + c0 * 8), 16, 0, 0);
    __builtin_amdgcn_global_load_lds(
        (const __attribute__((address_space(1))) unsigned int*)(B + (size_t)(col0 + r1c) * sK + k0 + q1c),
        (__attribute__((address_space(3))) unsigned int*)(Bs + c1 * 8), 16, 0, 0);
    __syncthreads();

    bf16x8 af[4], bfr[4];
#pragma unroll
    for (int i = 0; i < 4; i++)
      af[i] = *(const bf16x8*)(As + (wm * 64 + i * 16 + m16) * 32 + quad * 8);
#pragma unroll
    for (int j = 0; j < 4; j++)
      bfr[j] = *(const bf16x8*)(Bs + (wn * 64 + j * 16 + m16) * 32 + quad * 8);
#pragma unroll
    for (int i = 0; i < 4; i++)
#pragma unroll
      for (int j = 0; j < 4; j++)
        acc[i][j] = __builtin_amdgcn_mfma_f32_16x16x32_bf16(af[i], bfr[j], acc[i][j], 0, 0, 0);
    __syncthreads();
  }

#pragma unroll
  for (int i = 0; i < 4; i++) {
#pragma unroll
    for (int j = 0; j < 4; j++) {
      int rr = row0 + wm * 64 + i * 16 + quad * 4;
      int cc = col0 + wn * 64 + j * 16 + m16;
#pragma unroll
      for (int r = 0; r < 4; r++) {
        float g = acc[i][j][r];
        float rv = rn[(size_t)(rr + r) * N + cc];
        float hh = g / (1.f + __expf(-g)) * rv;
        Hb[(size_t)(rr + r) * N + cc] = f2bf(hh);
      }
    }
  }
}

// ---------------- alpha: block = 4 t-rows staged in LDS, loop 16 heads ------
__global__ __launch_bounds__(256) void alpha_kernel(const float* __restrict__ x,
                                                    const float* __restrict__ W_alpha,
                                                    const float* __restrict__ b_alpha,
                                                    const float* __restrict__ alpha_base,
                                                    float* __restrict__ a_raw) {
  __shared__ float xs[4][2048];
  int tid = threadIdx.x;
  int t0 = blockIdx.x * 4;
#pragma unroll
  for (int p = 0; p < 8; p++) {
    int idx = tid + p * 256;
    int row = idx >> 9, c4 = idx & 511;
    *(float4*)&xs[row][c4 * 4] = *(const float4*)(x + (size_t)(t0 + row) * DMODEL + c4 * 4);
  }
  __syncthreads();
  int w = tid >> 6, lane = tid & 63;
  int t = t0 + w;
#pragma unroll
  for (int h = 0; h < NHEADS; h++) {
    const float4* wr = (const float4*)(W_alpha + (size_t)h * DMODEL);
    float s = 0.f;
#pragma unroll
    for (int i = lane; i < 512; i += 64) {
      float4 a = *(const float4*)&xs[w][i * 4];
      float4 b = wr[i];
      s += a.x * b.x + a.y * b.y + a.z * b.z + a.w * b.w;
    }
#pragma unroll
    for (int off = 32; off > 0; off >>= 1) s += __shfl_down(s, off);
    if (lane == 0) {
      float sig = 1.f / (1.f + __expf(-(s + b_alpha[h])));
      a_raw[(size_t)h * SQLEN + t] = alpha_base[h] * 8.f * sig;
    }
  }
}

// ---------------- cumsum ----------------------------------------------------
__global__ __launch_bounds__(256) void cumsum_kernel(const float* __restrict__ a_raw,
                                                     float* __restrict__ A) {
  int h = blockIdx.x;
  __shared__ float part[256];
  int tid = threadIdx.x;
  float v[8];
  float s = 0.f;
#pragma unroll
  for (int i = 0; i < 8; i++) {
    v[i] = a_raw[(size_t)h * SQLEN + tid * 8 + i];
    s += v[i];
  }
  part[tid] = s;
  __syncthreads();
  for (int off = 1; off < 256; off <<= 1) {
    float tmp = (tid >= off) ? part[tid - off] : 0.f;
    __syncthreads();
    part[tid] += tmp;
    __syncthreads();
  }
  float run = (tid > 0) ? part[tid - 1] : 0.f;
#pragma unroll
  for (int i = 0; i < 8; i++) {
    run += v[i];
    A[(size_t)h * SQLEN + tid * 8 + i] = run;
  }
}

// ---------------- xPos: emit q,k,v directly as bf16 [h][t][d] ---------------
__global__ __launch_bounds__(256) void xpos_kernel(const float* __restrict__ qkv,
                                                   const float* __restrict__ a_raw,
                                                   const int* __restrict__ offset_p,
                                                   unsigned short* __restrict__ qb,
                                                   unsigned short* __restrict__ kb,
                                                   unsigned short* __restrict__ vb) {
  int idx = blockIdx.x * 256 + threadIdx.x;
  int j = idx & 63;
  int t = (idx >> 6) & 2047;
  int h = idx >> 17;
  float pos = (float)(t + offset_p[0]);
  float freq = exp2f(-(float)j * (13.287712379549449f / 64.f));
  float ang = pos * freq;
  float sn = __sinf(ang), cs = __cosf(ang);
  float zeta = (2.f * (float)j + 51.2f) / 179.2f;
  float lzp = __log2f(zeta) * pos * (1.f / 512.f);
  float sc = exp2f(lzp);
  float sci = exp2f(-lzp);
  const float* row = qkv + (size_t)t * (3 * DMODEL);
  int base = h * DHEAD + j;
  float q1 = row[base], q2 = row[base + 64];
  float k1 = row[DMODEL + base], k2 = row[DMODEL + base + 64];
  float v1 = row[2 * DMODEL + base], v2 = row[2 * DMODEL + base + 64];
  size_t o = ((size_t)h * SQLEN + t) * DHEAD + j;
  qb[o] = f2bf((q1 * cs - q2 * sn) * sc);
  qb[o + 64] = f2bf((q2 * cs + q1 * sn) * sc);
  float km = (1.f - __expf(a_raw[(size_t)h * SQLEN + t])) * sci;
  kb[o] = f2bf((k1 * cs - k2 * sn) * km);
  kb[o + 64] = f2bf((k2 * cs + k1 * sn) * km);
  vb[o] = f2bf(v1);
  vb[o + 64] = f2bf(v2);
}

// ------- transpose kb/vb [h][t][d] -> [h][d][t]; k gets exp(B-A[t]) scale ---
__global__ __launch_bounds__(256) void transpose_kv_kernel(const unsigned short* __restrict__ kb,
                                                           const unsigned short* __restrict__ vb,
                                                           const float* __restrict__ A,
                                                           unsigned short* __restrict__ kT,
                                                           unsigned short* __restrict__ vT) {
  __shared__ __align__(16) unsigned short tile[64][72];
  int h = blockIdx.z >> 1, sel = blockIdx.z & 1;
  int t0 = blockIdx.x * 64, d0 = blockIdx.y * 64;
  int tid = threadIdx.x;
  const unsigned short* src = (sel ? vb : kb) + ((size_t)h * SQLEN + t0) * DHEAD + d0;
  unsigned short* dst = (sel ? vT : kT) + (size_t)h * (DHEAD * SQLEN) + (size_t)d0 * SQLEN + t0;
  float B = A[(size_t)h * SQLEN + SQLEN - 1];
#pragma unroll
  for (int p = 0; p < 2; p++) {
    int c = tid + p * 256;
    int r = c >> 3, off = (c & 7) * 8;
    bf16x8 in = *(const bf16x8*)(src + (size_t)r * DHEAD + off);
    if (!sel) {
      float w = __expf(B - A[(size_t)h * SQLEN + t0 + r]);
      bf16x8 o;
#pragma unroll
      for (int j = 0; j < 8; j++) o[j] = (short)f2bf(bf2f((unsigned short)in[j]) * w);
      *(bf16x8*)&tile[r][off] = o;
    } else {
      *(bf16x8*)&tile[r][off] = in;
    }
  }
  __syncthreads();
#pragma unroll
  for (int p = 0; p < 2; p++) {
    int c = tid + p * 256;
    int dr = c >> 3, toff = (c & 7) * 8;
    bf16x8 o;
#pragma unroll
    for (int j = 0; j < 8; j++) o[j] = (short)tile[toff + j][dr];
    *(bf16x8*)(dst + (size_t)dr * SQLEN + toff) = o;
  }
}

// ---------------- transpose state -> stT bf16 [h][e][d] ---------------------
__global__ __launch_bounds__(256) void transpose_state_kernel(const float* __restrict__ st,
                                                              unsigned short* __restrict__ stT) {
  __shared__ float tile[64][65];
  int h = blockIdx.z, d0 = blockIdx.x * 64, e0 = blockIdx.y * 64;
  int tid = threadIdx.x;
  const float* src = st + (size_t)h * 16384 + (size_t)d0 * DHEAD + e0;
#pragma unroll
  for (int p = 0; p < 4; p++) {
    int idx = tid + p * 256;
    int r = idx >> 4, c = (idx & 15) * 4;
    float4 f = *(const float4*)(src + (size_t)r * DHEAD + c);
    tile[r][c] = f.x; tile[r][c + 1] = f.y; tile[r][c + 2] = f.z; tile[r][c + 3] = f.w;
  }
  __syncthreads();
  unsigned short* dst = stT + (size_t)h * 16384 + (size_t)e0 * DHEAD + d0;
#pragma unroll
  for (int p = 0; p < 2; p++) {
    int idx = tid + p * 256;
    int er = idx >> 3, doff = (idx & 7) * 8;
    bf16x8 o;
#pragma unroll
    for (int j = 0; j < 8; j++) o[j] = (short)f2bf(tile[doff + j][er]);
    *(bf16x8*)(dst + (size_t)er * DHEAD + doff) = o;
  }
}

// ---------------- retention v3: fused group-norm epilogue -------------------
__global__ __launch_bounds__(256) void retention_mfma(const unsigned short* __restrict__ qb,
                                                      const unsigned short* __restrict__ kb,
                                                      const unsigned short* __restrict__ vT,
                                                      const unsigned short* __restrict__ stT,
                                                      const float* __restrict__ A,
                                                      const float* __restrict__ gn_w,
                                                      const float* __restrict__ gn_b,
                                                      float* __restrict__ rn,
                                                      unsigned short* __restrict__ rnb) {
  __shared__ __align__(16) unsigned short ks[64 * 128];
  __shared__ __align__(16) unsigned short vs[128 * 64];
  __shared__ __align__(16) unsigned short Ss[64 * 72];
  __shared__ float djs[64];
  int h = blockIdx.x;
  int i0 = blockIdx.y * 64;
  int tid = threadIdx.x;
  int wave = tid >> 6, lane = tid & 63, quad = lane >> 4, m16 = lane & 15;
  const float* Ah = A + (size_t)h * SQLEN;
  float c = Ah[i0];
  int rq = wave * 16 + m16;

  const unsigned short* qh = qb + ((size_t)h * SQLEN + i0 + rq) * DHEAD;
  bf16x8 qf[4];
#pragma unroll
  for (int dc = 0; dc < 4; dc++)
    qf[dc] = *(const bf16x8*)(qh + dc * 32 + quad * 8);
  float ei = __expf(Ah[i0 + rq] - c);

  float wg[8], bg[8];
#pragma unroll
  for (int et = 0; et < 8; et++) {
    int col = h * DHEAD + et * 16 + m16;
    wg[et] = gn_w[col];
    bg[et] = gn_b[col];
  }

  floatx4 acc[8];
#pragma unroll
  for (int et = 0; et < 8; et++) acc[et] = (floatx4){0.f, 0.f, 0.f, 0.f};

  if (c > -87.f) {
    const unsigned short* sp = stT + (size_t)h * 16384;
    float ecr[4];
#pragma unroll
    for (int r = 0; r < 4; r++) ecr[r] = __expf(Ah[i0 + wave * 16 + quad * 4 + r]);
#pragma unroll
    for (int et = 0; et < 8; et++) {
#pragma unroll
      for (int dc = 0; dc < 4; dc++) {
        bf16x8 sf = *(const bf16x8*)(sp + (et * 16 + m16) * DHEAD + dc * 32 + quad * 8);
        acc[et] = __builtin_amdgcn_mfma_f32_16x16x32_bf16(qf[dc], sf, acc[et], 0, 0, 0);
      }
#pragma unroll
      for (int r = 0; r < 4; r++) acc[et][r] *= ecr[r];
    }
  }

  for (int j0 = 0; j0 <= i0; j0 += 64) {
    if (c - Ah[j0 + 63] < -87.f) continue;
    __syncthreads();
    const unsigned short* kh = kb + ((size_t)h * SQLEN + j0) * DHEAD;
    const unsigned short* vh = vT + (size_t)h * (DHEAD * SQLEN) + j0;
#pragma unroll
    for (int p = 0; p < 4; p++) {
      int cch = tid + p * 256;
      int r = cch >> 4, kp = (cch & 15) ^ (r & 7);
      __builtin_amdgcn_global_load_lds(
          (const __attribute__((address_space(1))) unsigned int*)(kh + (size_t)r * DHEAD + kp * 8),
          (__attribute__((address_space(3))) unsigned int*)(ks + cch * 8), 16, 0, 0);
      int e = cch >> 3, tp = (cch & 7) ^ (e & 7);
      __builtin_amdgcn_global_load_lds(
          (const __attribute__((address_space(1))) unsigned int*)(vh + (size_t)e * SQLEN + tp * 8),
          (__attribute__((address_space(3))) unsigned int*)(vs + cch * 8), 16, 0, 0);
    }
    if (tid < 64) djs[tid] = __expf(c - Ah[j0 + tid]);
    __syncthreads();

    bool diag = (j0 == i0);
#pragma unroll
    for (int jt = 0; jt < 4; jt++) {
      floatx4 s = (floatx4){0.f, 0.f, 0.f, 0.f};
#pragma unroll
      for (int dc = 0; dc < 4; dc++) {
        int rk = jt * 16 + m16;
        bf16x8 kf = *(const bf16x8*)(ks + rk * 128 + (((dc * 4 + quad) ^ (rk & 7)) * 8));
        s = __builtin_amdgcn_mfma_f32_16x16x32_bf16(kf, qf[dc], s, 0, 0, 0);
      }
      int jb = jt * 16 + quad * 4;
      float4 dj4 = *(const float4*)&djs[jb];
      ushort4 pk;
      pk.x = f2bf((diag && (jb + 0 > rq)) ? 0.f : s[0] * ei * dj4.x);
      pk.y = f2bf((diag && (jb + 1 > rq)) ? 0.f : s[1] * ei * dj4.y);
      pk.z = f2bf((diag && (jb + 2 > rq)) ? 0.f : s[2] * ei * dj4.z);
      pk.w = f2bf((diag && (jb + 3 > rq)) ? 0.f : s[3] * ei * dj4.w);
      *(ushort4*)(Ss + rq * 72 + jb) = pk;
    }

    bf16x8 sfr[2];
#pragma unroll
    for (int kc = 0; kc < 2; kc++)
      sfr[kc] = *(const bf16x8*)(Ss + rq * 72 + kc * 32 + quad * 8);
#pragma unroll
    for (int et = 0; et < 8; et++) {
#pragma unroll
      for (int kc = 0; kc < 2; kc++) {
        int e = et * 16 + m16;
        bf16x8 vf = *(const bf16x8*)(vs + e * 64 + (((kc * 4 + quad) ^ (e & 7)) * 8));
        acc[et] = __builtin_amdgcn_mfma_f32_16x16x32_bf16(sfr[kc], vf, acc[et], 0, 0, 0);
      }
    }
  }

#pragma unroll
  for (int r = 0; r < 4; r++) {
    float s = 0.f, ss = 0.f;
#pragma unroll
    for (int et = 0; et < 8; et++) {
      float v = acc[et][r];
      s += v; ss += v * v;
    }
#pragma unroll
    for (int off = 8; off > 0; off >>= 1) {
      s += __shfl_xor(s, off);
      ss += __shfl_xor(ss, off);
    }
    float mu = s * (1.f / 128.f);
    float var = ss * (1.f / 128.f) - mu * mu;
    float inv = rsqrtf(var + 1e-5f);
    int row = i0 + wave * 16 + quad * 4 + r;
    size_t o = (size_t)row * DMODEL + h * DHEAD;
#pragma unroll
    for (int et = 0; et < 8; et++) {
      float rv = (acc[et][r] - mu) * inv * wg[et] + bg[et];
      rn[o + et * 16 + m16] = rv;
      rnb[o + et * 16 + m16] = f2bf(rv);
    }
  }
}

// -------- new_state GEMM: P[h,chunk] = kT_s[:,krange] @ vT[:,krange]^T ------
__global__ __launch_bounds__(256) void state_gemm(const unsigned short* __restrict__ kT,
                                                  const unsigned short* __restrict__ vT,
                                                  float* __restrict__ P) {
  __shared__ __align__(16) unsigned short As[128 * 32];
  __shared__ __align__(16) unsigned short Bs[128 * 32];
  int chunk = blockIdx.x, h = blockIdx.y;
  int tid = threadIdx.x;
  int wave = tid >> 6, lane = tid & 63;
  int wm = wave >> 1, wn = wave & 1;
  int quad = lane >> 4, m16 = lane & 15;
  const unsigned short* Ab = kT + (size_t)h * (DHEAD * SQLEN);
  const unsigned short* Bb = vT + (size_t)h * (DHEAD * SQLEN);

  floatx4 acc[4][4];
#pragma unroll
  for (int i = 0; i < 4; i++)
#pragma unroll
    for (int j = 0; j < 4; j++) acc[i][j] = (floatx4){0.f, 0.f, 0.f, 0.f};

  int c0 = tid, c1 = tid + 256;
  int r0c = c0 >> 2, q0c = (c0 & 3) * 8;
  int r1c = c1 >> 2, q1c = (c1 & 3) * 8;

  for (int k0 = chunk * 256; k0 < chunk * 256 + 256; k0 += 32) {
    __builtin_amdgcn_global_load_lds(
        (const __attribute__((address_space(1))) unsigned int*)(Ab + (size_t)r0c * SQLEN + k0 + q0c),
        (__attribute__((address_space(3))) unsigned int*)(As + c0 * 8), 16, 0, 0);
    __builtin_amdgcn_global_load_lds(
        (const __attribute__((address_space(1))) unsigned int*)(Ab + (size_t)r1c * SQLEN + k0 + q1c),
        (__attribute__((address_space(3))) unsigned int*)(As + c1 * 8), 16, 0, 0);
    __builtin_amdgcn_global_load_lds(
        (const __attribute__((address_space(1))) unsigned int*)(Bb + (size_t)r0c * SQLEN + k0 + q0c),
        (__attribute__((address_space(3))) unsigned int*)(Bs + c0 * 8), 16, 0, 0);
    __builtin_amdgcn_global_load_lds(
        (const __attribute__((address_space(1))) unsigned int*)(Bb + (size_t)r1c * SQLEN + k0 + q1c),
        (__attribute__((address_space(3))) unsigned int*)(Bs + c1 * 8), 16, 0, 0);
    __syncthreads();

    bf16x8 af[4], bfr[4];
#pragma unroll
    for (int i = 0; i < 4; i++)
      af[i] = *(const bf16x8*)(As + (wm * 64 + i * 16 + m16) * 32 + quad * 8);
#pragma unroll
    for (int j = 0; j < 4; j++)
      bfr[j] = *(const bf16x8*)(Bs + (wn * 64 + j * 16 + m16) * 32 + quad * 8);
#pragma unroll
    for (int i = 0; i < 4; i++)
#pragma unroll
      for (int j = 0; j < 4; j++)
        acc[i][j] = __builtin_amdgcn_mfma_f32_16x16x32_bf16(af[i], bfr[j], acc[i][j], 0, 0, 0);
    __syncthreads();
  }

  float* Pp = P + (size_t)(h * 8 + chunk) * 16384;
#pragma unroll
  for (int i = 0; i < 4; i++)
#pragma unroll
    for (int j = 0; j < 4; j++) {
      int rr = wm * 64 + i * 16 + quad * 4;
      int cc = wn * 64 + j * 16 + m16;
#pragma unroll
      for (int r = 0; r < 4; r++)
        Pp[(size_t)(rr + r) * DHEAD + cc] = acc[i][j][r];
    }
}

__global__ __launch_bounds__(256) void state_combine(const float* __restrict__ P,
                                                     const float* __restrict__ state,
                                                     const float* __restrict__ A,
                                                     float* __restrict__ out_state) {
  int idx = blockIdx.x * 256 + threadIdx.x;
  int h = idx >> 14;
  int de = idx & 16383;
  float B = A[(size_t)h * SQLEN + SQLEN - 1];
  float s = __expf(B) * state[idx];
#pragma unroll
  for (int c = 0; c < 8; c++) s += P[(size_t)(h * 8 + c) * 16384 + de];
  out_state[idx] = s;
}

extern "C" void kernel_launch(void* const* d_in, const int* in_sizes, int n_in,
                              void* d_out, int out_size, void* d_ws, size_t ws_size,
                              hipStream_t stream) {
  const float* x = (const float*)d_in[0];
  const float* state = (const float*)d_in[1];
  const float* W_qkv = (const float*)d_in[2];
  const float* W_alpha = (const float*)d_in[3];
  const float* b_alpha = (const float*)d_in[4];
  const float* alpha_base = (const float*)d_in[5];
  const float* gn_w = (const float*)d_in[6];
  const float* gn_b = (const float*)d_in[7];
  const float* W_out = (const float*)d_in[8];
  const float* W_gate = (const float*)d_in[9];
  const int* offset = (const int*)d_in[10];

  float* ws = (float*)d_ws;
  float* qkv = ws;
  float* P   = ws + 4194304;
  float* rn  = ws + 29360128;
  float* araw = ws + 33554432;
  float* Acum = ws + 33587200;

  unsigned short* xb    = (unsigned short*)(ws + 12582912);
  unsigned short* Wqkvb = (unsigned short*)(ws + 16777216);
  unsigned short* qb    = (unsigned short*)(ws + 12582912);
  unsigned short* kb    = (unsigned short*)(ws + 14680064);
  unsigned short* vb    = (unsigned short*)(ws + 16777216);
  unsigned short* kT_s  = (unsigned short*)(ws + 18874368);
  unsigned short* vT_b  = (unsigned short*)(ws + 20971520);
  unsigned short* stT_b = (unsigned short*)(ws + 23068672);
  unsigned short* rnb   = (unsigned short*)(ws + 25165824);
  unsigned short* Wgateb = (unsigned short*)(ws + 14680064);
  unsigned short* Woutb  = (unsigned short*)(ws + 16777216);
  unsigned short* Hb     = (unsigned short*)(ws + 18874368);

  float* out = (float*)d_out;
  float* out_state = out + 4194304;

  dim3 blk(256);
  f2b2_kernel<<<dim3(16384), blk, 0, stream>>>((const float4*)x, (ushort4*)xb,
                                               (const float4*)W_qkv, (ushort4*)Wqkvb, 4096);
  // qkv GEMM: 256x256 8-phase pipelined kernel (512 threads, grid 24x8 = 192 wg)
  gemm256_nt<<<dim3(24, 8), dim3(512), 0, stream>>>(xb, Wqkvb, qkv, 2048, 6144, 2048);

  alpha_kernel<<<dim3(512), blk, 0, stream>>>(x, W_alpha, b_alpha, alpha_base, araw);
  cumsum_kernel<<<dim3(16), blk, 0, stream>>>(araw, Acum);
  xpos_kernel<<<dim3(8192), blk, 0, stream>>>(qkv, araw, offset, qb, kb, vb);
  transpose_kv_kernel<<<dim3(32, 2, 32), blk, 0, stream>>>(kb, vb, Acum, kT_s, vT_b);
  transpose_state_kernel<<<dim3(2, 2, 16), blk, 0, stream>>>(state, stT_b);

  retention_mfma<<<dim3(16, 32), blk, 0, stream>>>(qb, kb, vT_b, stT_b, Acum,
                                                   gn_w, gn_b, rn, rnb);
  state_gemm<<<dim3(8, 16), blk, 0, stream>>>(kT_s, vT_b, P);
  state_combine<<<dim3(1024), blk, 0, stream>>>(P, state, Acum, out_state);

  f2b2_kernel<<<dim3(8192), blk, 0, stream>>>((const float4*)W_gate, (ushort4*)Wgateb,
                                              (const float4*)W_out, (ushort4*)Woutb, 4096);
  gemm_swish_nt<<<dim3(16, 16), blk, 0, stream>>>(rnb, Wgateb, rn, Hb, 2048, 2048, 2048);
  gemm_bf16_nt<<<dim3(16, 16), blk, 0, stream>>>(Hb, Woutb, out, 2048, 2048, 2048);
}

// Round 4
// 414.675 us; speedup vs baseline: 1.0490x; 1.0107x over previous
//
#include <hip/hip_runtime.h>
#include <cstddef>

#define SQLEN 2048
#define DMODEL 2048
#define NHEADS 16
#define DHEAD 128

typedef __attribute__((ext_vector_type(8))) short bf16x8;
typedef __attribute__((ext_vector_type(4))) float floatx4;

__device__ __forceinline__ unsigned short f2bf(float f) {
  union { float f; unsigned u; } c; c.f = f;
  unsigned u = c.u;
  unsigned r = u + 0x7fffu + ((u >> 16) & 1u);
  return (unsigned short)(r >> 16);
}
__device__ __forceinline__ float bf2f(unsigned short s) {
  union { unsigned u; float f; } c; c.u = ((unsigned)s) << 16;
  return c.f;
}

// ---------------- fp32 -> bf16 convert (vectorized) -------------------------
__global__ __launch_bounds__(256) void f2b_kernel(const float4* __restrict__ in,
                                                  ushort4* __restrict__ out) {
  int i = blockIdx.x * 256 + threadIdx.x;
  float4 v = in[i];
  ushort4 o;
  o.x = f2bf(v.x); o.y = f2bf(v.y); o.z = f2bf(v.z); o.w = f2bf(v.w);
  out[i] = o;
}

// two-array variant (two tensors in one launch)
__global__ __launch_bounds__(256) void f2b2_kernel(const float4* __restrict__ in0,
                                                   ushort4* __restrict__ out0,
                                                   const float4* __restrict__ in1,
                                                   ushort4* __restrict__ out1,
                                                   int half_blocks) {
  int b = blockIdx.x;
  const float4* in = (b < half_blocks) ? in0 : in1;
  ushort4* out = (b < half_blocks) ? out0 : out1;
  int i = (b < half_blocks ? b : b - half_blocks) * 256 + threadIdx.x;
  float4 v = in[i];
  ushort4 o;
  o.x = f2bf(v.x); o.y = f2bf(v.y); o.z = f2bf(v.z); o.w = f2bf(v.w);
  out[i] = o;
}

// =================== 256x256 8-phase bf16 GEMM (C = A @ B^T) ================
// 512 thr / 8 waves (2M x 4N). LDS 128KiB: [buf][A,B][half 128x64] bf16.
// v2: register-held fragments across the 4 phases of a buffer pass:
//   p1: read A0+B0 -> Q(0,0); p2: read A1 -> Q(1,0); p3: read B1 -> Q(0,1);
//   p4: no ds reads -> Q(1,1).   24 ds_read_b128/wave/pass (was 48).
// Counted vmcnt(4) inside phases 4/8 before the mid-phase barrier.
// LDS read swizzle: 16B-slot ^= (row&7); source pre-swizzled to match.
#define GLD(srcp, dstp) __builtin_amdgcn_global_load_lds( \
    (const __attribute__((address_space(1))) unsigned int*)(srcp), \
    (__attribute__((address_space(3))) unsigned int*)(dstp), 16, 0, 0)

__global__ __launch_bounds__(512, 2) void gemm256_nt(const unsigned short* __restrict__ A,
                                                     const unsigned short* __restrict__ B,
                                                     float* __restrict__ C,
                                                     int M, int N, int K) {
  __shared__ __align__(16) unsigned short lds[65536];  // 128 KiB
  int tid = threadIdx.x;
  int wave = tid >> 6, lane = tid & 63;
  int wm = wave >> 2, wn = wave & 3;            // 2 x 4 wave grid
  int quad = lane >> 4, m16 = lane & 15;
  int sw = m16 & 7;

  // XCD-aware bijective swizzle (nwg % 8 == 0 guaranteed by launch config)
  int nTN = gridDim.x;
  int lin = blockIdx.y * nTN + blockIdx.x;
  int nwg = gridDim.x * gridDim.y;
  int swzb = (nwg & 7) == 0 ? ((lin & 7) * (nwg >> 3) + (lin >> 3)) : lin;
  int row0 = (swzb / nTN) * 256, col0 = (swzb % nTN) * 256;

  const int nkt = K >> 6;    // K-tiles of 64
  const int nit = K >> 7;    // loop iters (2 tiles each)

  // staging per-thread geometry: row = tid/8 (+64 for round 1), 16B slot = tid&7
  int srow = tid >> 3;
  int scol8 = (((tid & 7) ^ ((tid >> 3) & 7)) * 8);  // pre-swizzled global col

  bf16x8 a0[2][4], a1[2][4], bb[2][2];
  floatx4 acc[2][2][4][2];
#pragma unroll
  for (int a = 0; a < 2; a++)
#pragma unroll
    for (int b = 0; b < 2; b++)
#pragma unroll
      for (int c = 0; c < 4; c++)
#pragma unroll
        for (int d = 0; d < 2; d++) acc[a][b][c][d] = (floatx4){0.f, 0.f, 0.f, 0.f};

#define STAGE(t_, ab_, h_) do { \
    int t2_ = (t_); if (t2_ >= nkt) t2_ -= nkt; \
    const unsigned short* gp_ = (ab_) ? B : A; \
    int rb_ = ((ab_) ? col0 : row0) + (h_) * 128 + srow; \
    int kk_ = t2_ * 64 + scol8; \
    unsigned bs_ = ((unsigned)((t_) & 1)) * 32768u + (ab_) * 16384u + (h_) * 8192u; \
    GLD(gp_ + (size_t)rb_ * K + kk_, lds + bs_ + tid * 8); \
    GLD(gp_ + (size_t)(rb_ + 64) * K + kk_, lds + bs_ + 4096 + tid * 8); \
  } while (0)

#define VMW asm volatile("s_waitcnt vmcnt(4)" ::: "memory");

#define RDA(dst_, BUF_, MH_) do { \
    const unsigned short* Ab_ = lds + (BUF_) * 32768 + (MH_) * 8192; \
    _Pragma("unroll") for (int ks = 0; ks < 2; ks++) \
      _Pragma("unroll") for (int fi = 0; fi < 4; fi++) \
        dst_[ks][fi] = *(const bf16x8*)(Ab_ + (wm * 64 + fi * 16 + m16) * 64 + (((ks * 4 + quad) ^ sw) * 8)); \
  } while (0)

#define RDB(BUF_, NH_) do { \
    const unsigned short* Bb_ = lds + (BUF_) * 32768 + 16384 + (NH_) * 8192; \
    _Pragma("unroll") for (int ks = 0; ks < 2; ks++) \
      _Pragma("unroll") for (int gj = 0; gj < 2; gj++) \
        bb[ks][gj] = *(const bf16x8*)(Bb_ + (wn * 32 + gj * 16 + m16) * 64 + (((ks * 4 + quad) ^ sw) * 8)); \
  } while (0)

#define MM(A_, MH_, NH_) \
    _Pragma("unroll") for (int ks = 0; ks < 2; ks++) \
      _Pragma("unroll") for (int fi = 0; fi < 4; fi++) \
        _Pragma("unroll") for (int gj = 0; gj < 2; gj++) \
          acc[MH_][NH_][fi][gj] = __builtin_amdgcn_mfma_f32_16x16x32_bf16( \
              A_[ks][fi], bb[ks][gj], acc[MH_][NH_][fi][gj], 0, 0, 0);

#define PH(RD_, STG_, W_, MM_) do { \
    RD_; \
    STG_; \
    W_ \
    __builtin_amdgcn_s_barrier(); \
    asm volatile("s_waitcnt lgkmcnt(0)" ::: "memory"); \
    __builtin_amdgcn_sched_barrier(0); \
    __builtin_amdgcn_s_setprio(1); \
    MM_ \
    __builtin_amdgcn_s_setprio(0); \
    __builtin_amdgcn_sched_barrier(0); \
    __builtin_amdgcn_s_barrier(); \
  } while (0)

  // prologue: T0 fully + T1.B0 + T1.A0  (stream pos matches steady state)
  STAGE(0, 1, 0);
  STAGE(0, 0, 0);
  STAGE(0, 0, 1);
  STAGE(0, 1, 1);
  STAGE(1, 1, 0);
  STAGE(1, 0, 0);
  asm volatile("s_waitcnt vmcnt(4)" ::: "memory");  // T0 landed (own wave)
  __builtin_amdgcn_s_barrier();                     // -> landed globally

  for (int it = 0; it < nit; ++it) {
    int T = it * 2;
    PH(RDA(a0, 0, 0); RDB(0, 0), STAGE(T + 1, 0, 1), , MM(a0, 0, 0));
    PH(RDA(a1, 0, 1),            STAGE(T + 1, 1, 1), , MM(a1, 1, 0));
    PH(RDB(0, 1),                STAGE(T + 2, 1, 0), , MM(a0, 0, 1));
    PH(,                         STAGE(T + 2, 0, 0), VMW, MM(a1, 1, 1));
    PH(RDA(a0, 1, 0); RDB(1, 0), STAGE(T + 2, 0, 1), , MM(a0, 0, 0));
    PH(RDA(a1, 1, 1),            STAGE(T + 2, 1, 1), , MM(a1, 1, 0));
    PH(RDB(1, 1),                STAGE(T + 3, 1, 0), , MM(a0, 0, 1));
    PH(,                         STAGE(T + 3, 0, 0), VMW, MM(a1, 1, 1));
  }

#pragma unroll
  for (int mh = 0; mh < 2; mh++)
#pragma unroll
    for (int nh = 0; nh < 2; nh++)
#pragma unroll
      for (int fi = 0; fi < 4; fi++)
#pragma unroll
        for (int gj = 0; gj < 2; gj++) {
          int rr = row0 + mh * 128 + wm * 64 + fi * 16 + quad * 4;
          int cc = col0 + nh * 128 + wn * 32 + gj * 16 + m16;
#pragma unroll
          for (int r = 0; r < 4; r++)
            C[(size_t)(rr + r) * N + cc] = acc[mh][nh][fi][gj][r];
        }
#undef PH
#undef MM
#undef RDB
#undef RDA
#undef VMW
#undef STAGE
}

// ---------------- bf16 MFMA GEMM: C[M,N] = A[M,K] @ B[N,K]^T ----------------
__global__ __launch_bounds__(256) void gemm_bf16_nt(const unsigned short* __restrict__ A,
                                                    const unsigned short* __restrict__ B,
                                                    float* __restrict__ C,
                                                    int M, int N, int K) {
  __shared__ __align__(16) unsigned short As[128 * 32];
  __shared__ __align__(16) unsigned short Bs[128 * 32];
  int tid = threadIdx.x;
  int wave = tid >> 6;
  int lane = tid & 63;
  int wm = wave >> 1, wn = wave & 1;
  int quad = lane >> 4, m16 = lane & 15;
  int row0 = blockIdx.y * 128, col0 = blockIdx.x * 128;

  floatx4 acc[4][4];
#pragma unroll
  for (int i = 0; i < 4; i++)
#pragma unroll
    for (int j = 0; j < 4; j++) acc[i][j] = (floatx4){0.f, 0.f, 0.f, 0.f};

  int c0 = tid, c1 = tid + 256;
  int r0c = c0 >> 2, q0c = (c0 & 3) * 8;
  int r1c = c1 >> 2, q1c = (c1 & 3) * 8;

  const size_t sK = (size_t)K;
  for (int k0 = 0; k0 < K; k0 += 32) {
    __builtin_amdgcn_global_load_lds(
        (const __attribute__((address_space(1))) unsigned int*)(A + (size_t)(row0 + r0c) * sK + k0 + q0c),
        (__attribute__((address_space(3))) unsigned int*)(As + c0 * 8), 16, 0, 0);
    __builtin_amdgcn_global_load_lds(
        (const __attribute__((address_space(1))) unsigned int*)(A + (size_t)(row0 + r1c) * sK + k0 + q1c),
        (__attribute__((address_space(3))) unsigned int*)(As + c1 * 8), 16, 0, 0);
    __builtin_amdgcn_global_load_lds(
        (const __attribute__((address_space(1))) unsigned int*)(B + (size_t)(col0 + r0c) * sK + k0 + q0c),
        (__attribute__((address_space(3))) unsigned int*)(Bs + c0 * 8), 16, 0, 0);
    __builtin_amdgcn_global_load_lds(
        (const __attribute__((address_space(1))) unsigned int*)(B + (size_t)(col0 + r1c) * sK + k0 + q1c),
        (__attribute__((address_space(3))) unsigned int*)(Bs + c1 * 8), 16, 0, 0);
    __syncthreads();

    bf16x8 af[4], bfr[4];
#pragma unroll
    for (int i = 0; i < 4; i++)
      af[i] = *(const bf16x8*)(As + (wm * 64 + i * 16 + m16) * 32 + quad * 8);
#pragma unroll
    for (int j = 0; j < 4; j++)
      bfr[j] = *(const bf16x8*)(Bs + (wn * 64 + j * 16 + m16) * 32 + quad * 8);
#pragma unroll
    for (int i = 0; i < 4; i++)
#pragma unroll
      for (int j = 0; j < 4; j++)
        acc[i][j] = __builtin_amdgcn_mfma_f32_16x16x32_bf16(af[i], bfr[j], acc[i][j], 0, 0, 0);
    __syncthreads();
  }

#pragma unroll
  for (int i = 0; i < 4; i++) {
#pragma unroll
    for (int j = 0; j < 4; j++) {
      int rr = row0 + wm * 64 + i * 16 + quad * 4;
      int cc = col0 + wn * 64 + j * 16 + m16;
#pragma unroll
      for (int r = 0; r < 4; r++)
        C[(size_t)(rr + r) * N + cc] = acc[i][j][r];
    }
  }
}

// ------- gate GEMM with fused swish*rn epilogue, bf16 output ---------------
__global__ __launch_bounds__(256) void gemm_swish_nt(const unsigned short* __restrict__ A,
                                                     const unsigned short* __restrict__ B,
                                                     const float* __restrict__ rn,
                                                     unsigned short* __restrict__ Hb,
                                                     int M, int N, int K) {
  __shared__ __align__(16) unsigned short As[128 * 32];
  __shared__ __align__(16) unsigned short Bs[128 * 32];
  int tid = threadIdx.x;
  int wave = tid >> 6;
  int lane = tid & 63;
  int wm = wave >> 1, wn = wave & 1;
  int quad = lane >> 4, m16 = lane & 15;
  int row0 = blockIdx.y * 128, col0 = blockIdx.x * 128;

  floatx4 acc[4][4];
#pragma unroll
  for (int i = 0; i < 4; i++)
#pragma unroll
    for (int j = 0; j < 4; j++) acc[i][j] = (floatx4){0.f, 0.f, 0.f, 0.f};

  int c0 = tid, c1 = tid + 256;
  int r0c = c0 >> 2, q0c = (c0 & 3) * 8;
  int r1c = c1 >> 2, q1c = (c1 & 3) * 8;

  const size_t sK = (size_t)K;
  for (int k0 = 0; k0 < K; k0 += 32) {
    __builtin_amdgcn_global_load_lds(
        (const __attribute__((address_space(1))) unsigned int*)(A + (size_t)(row0 + r0c) * sK + k0 + q0c),
        (__attribute__((address_space(3))) unsigned int*)(As + c0 * 8), 16, 0, 0);
    __builtin_amdgcn_global_load_lds(
        (const __attribute__((address_space(1))) unsigned int*)(A + (size_t)(row0 + r1c) * sK + k0 + q1c),
        (__attribute__((address_space(3))) unsigned int*)(As + c1 * 8), 16, 0, 0);
    __builtin_amdgcn_global_load_lds(
        (const __attribute__((address_space(1))) unsigned int*)(B + (size_t)(col0 + r0c) * sK + k0 + q0c),
        (__attribute__((address_space(3))) unsigned int*)(Bs + c0 * 8), 16, 0, 0);
    __builtin_amdgcn_global_load_lds(
        (const __attribute__((address_space(1))) unsigned int*)(B + (size_t)(col0 + r1c) * sK + k0 + q1c),
        (__attribute__((address_space(3))) unsigned int*)(Bs + c1 * 8), 16, 0, 0);
    __syncthreads();

    bf16x8 af[4], bfr[4];
#pragma unroll
    for (int i = 0; i < 4; i++)
      af[i] = *(const bf16x8*)(As + (wm * 64 + i * 16 + m16) * 32 + quad * 8);
#pragma unroll
    for (int j = 0; j < 4; j++)
      bfr[j] = *(const bf16x8*)(Bs + (wn * 64 + j * 16 + m16) * 32 + quad * 8);
#pragma unroll
    for (int i = 0; i < 4; i++)
#pragma unroll
      for (int j = 0; j < 4; j++)
        acc[i][j] = __builtin_amdgcn_mfma_f32_16x16x32_bf16(af[i], bfr[j], acc[i][j], 0, 0, 0);
    __syncthreads();
  }

#pragma unroll
  for (int i = 0; i < 4; i++) {
#pragma unroll
    for (int j = 0; j < 4; j++) {
      int rr = row0 + wm * 64 + i * 16 + quad * 4;
      int cc = col0 + wn * 64 + j * 16 + m16;
#pragma unroll
      for (int r = 0; r < 4; r++) {
        float g = acc[i][j][r];
        float rv = rn[(size_t)(rr + r) * N + cc];
        float hh = g / (1.f + __expf(-g)) * rv;
        Hb[(size_t)(rr + r) * N + cc] = f2bf(hh);
      }
    }
  }
}

// ---------------- alpha: block = 4 t-rows staged in LDS, loop 16 heads ------
__global__ __launch_bounds__(256) void alpha_kernel(const float* __restrict__ x,
                                                    const float* __restrict__ W_alpha,
                                                    const float* __restrict__ b_alpha,
                                                    const float* __restrict__ alpha_base,
                                                    float* __restrict__ a_raw) {
  __shared__ float xs[4][2048];
  int tid = threadIdx.x;
  int t0 = blockIdx.x * 4;
#pragma unroll
  for (int p = 0; p < 8; p++) {
    int idx = tid + p * 256;
    int row = idx >> 9, c4 = idx & 511;
    *(float4*)&xs[row][c4 * 4] = *(const float4*)(x + (size_t)(t0 + row) * DMODEL + c4 * 4);
  }
  __syncthreads();
  int w = tid >> 6, lane = tid & 63;
  int t = t0 + w;
#pragma unroll
  for (int h = 0; h < NHEADS; h++) {
    const float4* wr = (const float4*)(W_alpha + (size_t)h * DMODEL);
    float s = 0.f;
#pragma unroll
    for (int i = lane; i < 512; i += 64) {
      float4 a = *(const float4*)&xs[w][i * 4];
      float4 b = wr[i];
      s += a.x * b.x + a.y * b.y + a.z * b.z + a.w * b.w;
    }
#pragma unroll
    for (int off = 32; off > 0; off >>= 1) s += __shfl_down(s, off);
    if (lane == 0) {
      float sig = 1.f / (1.f + __expf(-(s + b_alpha[h])));
      a_raw[(size_t)h * SQLEN + t] = alpha_base[h] * 8.f * sig;
    }
  }
}

// ---------------- cumsum ----------------------------------------------------
__global__ __launch_bounds__(256) void cumsum_kernel(const float* __restrict__ a_raw,
                                                     float* __restrict__ A) {
  int h = blockIdx.x;
  __shared__ float part[256];
  int tid = threadIdx.x;
  float v[8];
  float s = 0.f;
#pragma unroll
  for (int i = 0; i < 8; i++) {
    v[i] = a_raw[(size_t)h * SQLEN + tid * 8 + i];
    s += v[i];
  }
  part[tid] = s;
  __syncthreads();
  for (int off = 1; off < 256; off <<= 1) {
    float tmp = (tid >= off) ? part[tid - off] : 0.f;
    __syncthreads();
    part[tid] += tmp;
    __syncthreads();
  }
  float run = (tid > 0) ? part[tid - 1] : 0.f;
#pragma unroll
  for (int i = 0; i < 8; i++) {
    run += v[i];
    A[(size_t)h * SQLEN + tid * 8 + i] = run;
  }
}

// ---------------- xPos: emit q,k,v directly as bf16 [h][t][d] ---------------
__global__ __launch_bounds__(256) void xpos_kernel(const float* __restrict__ qkv,
                                                   const float* __restrict__ a_raw,
                                                   const int* __restrict__ offset_p,
                                                   unsigned short* __restrict__ qb,
                                                   unsigned short* __restrict__ kb,
                                                   unsigned short* __restrict__ vb) {
  int idx = blockIdx.x * 256 + threadIdx.x;
  int j = idx & 63;
  int t = (idx >> 6) & 2047;
  int h = idx >> 17;
  float pos = (float)(t + offset_p[0]);
  float freq = exp2f(-(float)j * (13.287712379549449f / 64.f));
  float ang = pos * freq;
  float sn = __sinf(ang), cs = __cosf(ang);
  float zeta = (2.f * (float)j + 51.2f) / 179.2f;
  float lzp = __log2f(zeta) * pos * (1.f / 512.f);
  float sc = exp2f(lzp);
  float sci = exp2f(-lzp);
  const float* row = qkv + (size_t)t * (3 * DMODEL);
  int base = h * DHEAD + j;
  float q1 = row[base], q2 = row[base + 64];
  float k1 = row[DMODEL + base], k2 = row[DMODEL + base + 64];
  float v1 = row[2 * DMODEL + base], v2 = row[2 * DMODEL + base + 64];
  size_t o = ((size_t)h * SQLEN + t) * DHEAD + j;
  qb[o] = f2bf((q1 * cs - q2 * sn) * sc);
  qb[o + 64] = f2bf((q2 * cs + q1 * sn) * sc);
  float km = (1.f - __expf(a_raw[(size_t)h * SQLEN + t])) * sci;
  kb[o] = f2bf((k1 * cs - k2 * sn) * km);
  kb[o + 64] = f2bf((k2 * cs + k1 * sn) * km);
  vb[o] = f2bf(v1);
  vb[o + 64] = f2bf(v2);
}

// ------- transpose kb/vb [h][t][d] -> [h][d][t]; k gets exp(B-A[t]) scale ---
__global__ __launch_bounds__(256) void transpose_kv_kernel(const unsigned short* __restrict__ kb,
                                                           const unsigned short* __restrict__ vb,
                                                           const float* __restrict__ A,
                                                           unsigned short* __restrict__ kT,
                                                           unsigned short* __restrict__ vT) {
  __shared__ __align__(16) unsigned short tile[64][72];
  int h = blockIdx.z >> 1, sel = blockIdx.z & 1;
  int t0 = blockIdx.x * 64, d0 = blockIdx.y * 64;
  int tid = threadIdx.x;
  const unsigned short* src = (sel ? vb : kb) + ((size_t)h * SQLEN + t0) * DHEAD + d0;
  unsigned short* dst = (sel ? vT : kT) + (size_t)h * (DHEAD * SQLEN) + (size_t)d0 * SQLEN + t0;
  float B = A[(size_t)h * SQLEN + SQLEN - 1];
#pragma unroll
  for (int p = 0; p < 2; p++) {
    int c = tid + p * 256;
    int r = c >> 3, off = (c & 7) * 8;
    bf16x8 in = *(const bf16x8*)(src + (size_t)r * DHEAD + off);
    if (!sel) {
      float w = __expf(B - A[(size_t)h * SQLEN + t0 + r]);
      bf16x8 o;
#pragma unroll
      for (int j = 0; j < 8; j++) o[j] = (short)f2bf(bf2f((unsigned short)in[j]) * w);
      *(bf16x8*)&tile[r][off] = o;
    } else {
      *(bf16x8*)&tile[r][off] = in;
    }
  }
  __syncthreads();
#pragma unroll
  for (int p = 0; p < 2; p++) {
    int c = tid + p * 256;
    int dr = c >> 3, toff = (c & 7) * 8;
    bf16x8 o;
#pragma unroll
    for (int j = 0; j < 8; j++) o[j] = (short)tile[toff + j][dr];
    *(bf16x8*)(dst + (size_t)dr * SQLEN + toff) = o;
  }
}

// ---------------- transpose state -> stT bf16 [h][e][d] ---------------------
__global__ __launch_bounds__(256) void transpose_state_kernel(const float* __restrict__ st,
                                                              unsigned short* __restrict__ stT) {
  __shared__ float tile[64][65];
  int h = blockIdx.z, d0 = blockIdx.x * 64, e0 = blockIdx.y * 64;
  int tid = threadIdx.x;
  const float* src = st + (size_t)h * 16384 + (size_t)d0 * DHEAD + e0;
#pragma unroll
  for (int p = 0; p < 4; p++) {
    int idx = tid + p * 256;
    int r = idx >> 4, c = (idx & 15) * 4;
    float4 f = *(const float4*)(src + (size_t)r * DHEAD + c);
    tile[r][c] = f.x; tile[r][c + 1] = f.y; tile[r][c + 2] = f.z; tile[r][c + 3] = f.w;
  }
  __syncthreads();
  unsigned short* dst = stT + (size_t)h * 16384 + (size_t)e0 * DHEAD + d0;
#pragma unroll
  for (int p = 0; p < 2; p++) {
    int idx = tid + p * 256;
    int er = idx >> 3, doff = (idx & 7) * 8;
    bf16x8 o;
#pragma unroll
    for (int j = 0; j < 8; j++) o[j] = (short)f2bf(tile[doff + j][er]);
    *(bf16x8*)(dst + (size_t)er * DHEAD + doff) = o;
  }
}

// ---------------- retention v4: double-buffered K/V staging -----------------
// T3-lite 2-phase: issue next tile's global_load_lds before the barrier,
// counted vmcnt(8) (in-order retirement => current tile landed), compute,
// barrier, flip. j_start via one wave-parallel ballot (decay cutoff is a
// monotone prefix since A is strictly decreasing).
__global__ __launch_bounds__(256) void retention_mfma(const unsigned short* __restrict__ qb,
                                                      const unsigned short* __restrict__ kb,
                                                      const unsigned short* __restrict__ vT,
                                                      const unsigned short* __restrict__ stT,
                                                      const float* __restrict__ A,
                                                      const float* __restrict__ gn_w,
                                                      const float* __restrict__ gn_b,
                                                      float* __restrict__ rn,
                                                      unsigned short* __restrict__ rnb) {
  __shared__ __align__(16) unsigned short ks[2][64 * 128];
  __shared__ __align__(16) unsigned short vs[2][128 * 64];
  __shared__ __align__(16) unsigned short Ss[64 * 72];
  __shared__ float djs[2][64];
  int h = blockIdx.x;
  int i0 = blockIdx.y * 64;
  int tid = threadIdx.x;
  int wave = tid >> 6, lane = tid & 63, quad = lane >> 4, m16 = lane & 15;
  const float* Ah = A + (size_t)h * SQLEN;
  float c = Ah[i0];
  int rq = wave * 16 + m16;

  const unsigned short* qh = qb + ((size_t)h * SQLEN + i0 + rq) * DHEAD;
  bf16x8 qf[4];
#pragma unroll
  for (int dc = 0; dc < 4; dc++)
    qf[dc] = *(const bf16x8*)(qh + dc * 32 + quad * 8);
  float ei = __expf(Ah[i0 + rq] - c);

  float wg[8], bg[8];
#pragma unroll
  for (int et = 0; et < 8; et++) {
    int col = h * DHEAD + et * 16 + m16;
    wg[et] = gn_w[col];
    bg[et] = gn_b[col];
  }

  // wave-parallel scan for first non-skipped j-tile (prefix is monotone)
  bool skipl = false;
  if (lane < 32) {
    int j0l = lane * 64;
    if (j0l <= i0) skipl = (c - Ah[j0l + 63] < -87.f);
  }
  unsigned long long smask = __ballot(skipl);
  int j_start = 64 * (int)__builtin_ctzll(~smask);

  floatx4 acc[8];
#pragma unroll
  for (int et = 0; et < 8; et++) acc[et] = (floatx4){0.f, 0.f, 0.f, 0.f};

  const unsigned short* khb = kb + (size_t)h * SQLEN * DHEAD;
  const unsigned short* vhb = vT + (size_t)h * (DHEAD * SQLEN);

#define STAGE_KV(b_, j0_) do { \
    const unsigned short* kh_ = khb + (size_t)(j0_) * DHEAD; \
    const unsigned short* vh_ = vhb + (j0_); \
    _Pragma("unroll") for (int p = 0; p < 4; p++) { \
      int cch = tid + p * 256; \
      int r_ = cch >> 4, kp_ = (cch & 15) ^ (r_ & 7); \
      GLD(kh_ + (size_t)r_ * DHEAD + kp_ * 8, &ks[b_][0] + cch * 8); \
      int e_ = cch >> 3, tp_ = (cch & 7) ^ (e_ & 7); \
      GLD(vh_ + (size_t)e_ * SQLEN + tp_ * 8, &vs[b_][0] + cch * 8); \
    } \
  } while (0)

  // prologue: stage first tile; latency hides under the cross-state term
  STAGE_KV(0, j_start);
  if (tid < 64) djs[0][tid] = __expf(c - Ah[j_start + tid]);

  // cross term with initial state: exp(Ai) * q @ stT
  if (c > -87.f) {
    const unsigned short* sp = stT + (size_t)h * 16384;
    float ecr[4];
#pragma unroll
    for (int r = 0; r < 4; r++) ecr[r] = __expf(Ah[i0 + wave * 16 + quad * 4 + r]);
#pragma unroll
    for (int et = 0; et < 8; et++) {
#pragma unroll
      for (int dc = 0; dc < 4; dc++) {
        bf16x8 sf = *(const bf16x8*)(sp + (et * 16 + m16) * DHEAD + dc * 32 + quad * 8);
        acc[et] = __builtin_amdgcn_mfma_f32_16x16x32_bf16(qf[dc], sf, acc[et], 0, 0, 0);
      }
#pragma unroll
      for (int r = 0; r < 4; r++) acc[et][r] *= ecr[r];
    }
  }

  int cur = 0;
  for (int j0 = j_start; j0 <= i0; j0 += 64) {
    int nxt = j0 + 64;
    if (nxt <= i0) {
      STAGE_KV(cur ^ 1, nxt);
      if (tid < 64) djs[cur ^ 1][tid] = __expf(c - Ah[nxt + tid]);
      asm volatile("s_waitcnt vmcnt(8)" ::: "memory");  // cur's 8 landed (own wave)
    } else {
      asm volatile("s_waitcnt vmcnt(0)" ::: "memory");
    }
    __syncthreads();  // -> landed globally; also guards djs slot reuse

    bool diag = (j0 == i0);
    const unsigned short* ksc = &ks[cur][0];
    const unsigned short* vsc = &vs[cur][0];
#pragma unroll
    for (int jt = 0; jt < 4; jt++) {
      floatx4 s = (floatx4){0.f, 0.f, 0.f, 0.f};
#pragma unroll
      for (int dc = 0; dc < 4; dc++) {
        int rk = jt * 16 + m16;
        bf16x8 kf = *(const bf16x8*)(ksc + rk * 128 + (((dc * 4 + quad) ^ (rk & 7)) * 8));
        s = __builtin_amdgcn_mfma_f32_16x16x32_bf16(kf, qf[dc], s, 0, 0, 0);
      }
      int jb = jt * 16 + quad * 4;
      float4 dj4 = *(const float4*)&djs[cur][jb];
      ushort4 pk;
      pk.x = f2bf((diag && (jb + 0 > rq)) ? 0.f : s[0] * ei * dj4.x);
      pk.y = f2bf((diag && (jb + 1 > rq)) ? 0.f : s[1] * ei * dj4.y);
      pk.z = f2bf((diag && (jb + 2 > rq)) ? 0.f : s[2] * ei * dj4.z);
      pk.w = f2bf((diag && (jb + 3 > rq)) ? 0.f : s[3] * ei * dj4.w);
      *(ushort4*)(Ss + rq * 72 + jb) = pk;
    }

    bf16x8 sfr[2];
#pragma unroll
    for (int kc = 0; kc < 2; kc++)
      sfr[kc] = *(const bf16x8*)(Ss + rq * 72 + kc * 32 + quad * 8);
#pragma unroll
    for (int et = 0; et < 8; et++) {
#pragma unroll
      for (int kc = 0; kc < 2; kc++) {
        int e = et * 16 + m16;
        bf16x8 vf = *(const bf16x8*)(vsc + e * 64 + (((kc * 4 + quad) ^ (e & 7)) * 8));
        acc[et] = __builtin_amdgcn_mfma_f32_16x16x32_bf16(sfr[kc], vf, acc[et], 0, 0, 0);
      }
    }
    __syncthreads();  // reads of buf[cur] done before next iter restages it
    cur ^= 1;
  }
#undef STAGE_KV

#pragma unroll
  for (int r = 0; r < 4; r++) {
    float s = 0.f, ss = 0.f;
#pragma unroll
    for (int et = 0; et < 8; et++) {
      float v = acc[et][r];
      s += v; ss += v * v;
    }
#pragma unroll
    for (int off = 8; off > 0; off >>= 1) {
      s += __shfl_xor(s, off);
      ss += __shfl_xor(ss, off);
    }
    float mu = s * (1.f / 128.f);
    float var = ss * (1.f / 128.f) - mu * mu;
    float inv = rsqrtf(var + 1e-5f);
    int row = i0 + wave * 16 + quad * 4 + r;
    size_t o = (size_t)row * DMODEL + h * DHEAD;
#pragma unroll
    for (int et = 0; et < 8; et++) {
      float rv = (acc[et][r] - mu) * inv * wg[et] + bg[et];
      rn[o + et * 16 + m16] = rv;
      rnb[o + et * 16 + m16] = f2bf(rv);
    }
  }
}

// -------- new_state GEMM: P[h,chunk] = kT_s[:,krange] @ vT[:,krange]^T ------
__global__ __launch_bounds__(256) void state_gemm(const unsigned short* __restrict__ kT,
                                                  const unsigned short* __restrict__ vT,
                                                  float* __restrict__ P) {
  __shared__ __align__(16) unsigned short As[128 * 32];
  __shared__ __align__(16) unsigned short Bs[128 * 32];
  int chunk = blockIdx.x, h = blockIdx.y;
  int tid = threadIdx.x;
  int wave = tid >> 6, lane = tid & 63;
  int wm = wave >> 1, wn = wave & 1;
  int quad = lane >> 4, m16 = lane & 15;
  const unsigned short* Ab = kT + (size_t)h * (DHEAD * SQLEN);
  const unsigned short* Bb = vT + (size_t)h * (DHEAD * SQLEN);

  floatx4 acc[4][4];
#pragma unroll
  for (int i = 0; i < 4; i++)
#pragma unroll
    for (int j = 0; j < 4; j++) acc[i][j] = (floatx4){0.f, 0.f, 0.f, 0.f};

  int c0 = tid, c1 = tid + 256;
  int r0c = c0 >> 2, q0c = (c0 & 3) * 8;
  int r1c = c1 >> 2, q1c = (c1 & 3) * 8;

  for (int k0 = chunk * 256; k0 < chunk * 256 + 256; k0 += 32) {
    __builtin_amdgcn_global_load_lds(
        (const __attribute__((address_space(1))) unsigned int*)(Ab + (size_t)r0c * SQLEN + k0 + q0c),
        (__attribute__((address_space(3))) unsigned int*)(As + c0 * 8), 16, 0, 0);
    __builtin_amdgcn_global_load_lds(
        (const __attribute__((address_space(1))) unsigned int*)(Ab + (size_t)r1c * SQLEN + k0 + q1c),
        (__attribute__((address_space(3))) unsigned int*)(As + c1 * 8), 16, 0, 0);
    __builtin_amdgcn_global_load_lds(
        (const __attribute__((address_space(1))) unsigned int*)(Bb + (size_t)r0c * SQLEN + k0 + q0c),
        (__attribute__((address_space(3))) unsigned int*)(Bs + c0 * 8), 16, 0, 0);
    __builtin_amdgcn_global_load_lds(
        (const __attribute__((address_space(1))) unsigned int*)(Bb + (size_t)r1c * SQLEN + k0 + q1c),
        (__attribute__((address_space(3))) unsigned int*)(Bs + c1 * 8), 16, 0, 0);
    __syncthreads();

    bf16x8 af[4], bfr[4];
#pragma unroll
    for (int i = 0; i < 4; i++)
      af[i] = *(const bf16x8*)(As + (wm * 64 + i * 16 + m16) * 32 + quad * 8);
#pragma unroll
    for (int j = 0; j < 4; j++)
      bfr[j] = *(const bf16x8*)(Bs + (wn * 64 + j * 16 + m16) * 32 + quad * 8);
#pragma unroll
    for (int i = 0; i < 4; i++)
#pragma unroll
      for (int j = 0; j < 4; j++)
        acc[i][j] = __builtin_amdgcn_mfma_f32_16x16x32_bf16(af[i], bfr[j], acc[i][j], 0, 0, 0);
    __syncthreads();
  }

  float* Pp = P + (size_t)(h * 8 + chunk) * 16384;
#pragma unroll
  for (int i = 0; i < 4; i++)
#pragma unroll
    for (int j = 0; j < 4; j++) {
      int rr = wm * 64 + i * 16 + quad * 4;
      int cc = wn * 64 + j * 16 + m16;
#pragma unroll
      for (int r = 0; r < 4; r++)
        Pp[(size_t)(rr + r) * DHEAD + cc] = acc[i][j][r];
    }
}

__global__ __launch_bounds__(256) void state_combine(const float* __restrict__ P,
                                                     const float* __restrict__ state,
                                                     const float* __restrict__ A,
                                                     float* __restrict__ out_state) {
  int idx = blockIdx.x * 256 + threadIdx.x;
  int h = idx >> 14;
  int de = idx & 16383;
  float B = A[(size_t)h * SQLEN + SQLEN - 1];
  float s = __expf(B) * state[idx];
#pragma unroll
  for (int c = 0; c < 8; c++) s += P[(size_t)(h * 8 + c) * 16384 + de];
  out_state[idx] = s;
}

extern "C" void kernel_launch(void* const* d_in, const int* in_sizes, int n_in,
                              void* d_out, int out_size, void* d_ws, size_t ws_size,
                              hipStream_t stream) {
  const float* x = (const float*)d_in[0];
  const float* state = (const float*)d_in[1];
  const float* W_qkv = (const float*)d_in[2];
  const float* W_alpha = (const float*)d_in[3];
  const float* b_alpha = (const float*)d_in[4];
  const float* alpha_base = (const float*)d_in[5];
  const float* gn_w = (const float*)d_in[6];
  const float* gn_b = (const float*)d_in[7];
  const float* W_out = (const float*)d_in[8];
  const float* W_gate = (const float*)d_in[9];
  const int* offset = (const int*)d_in[10];

  float* ws = (float*)d_ws;
  float* qkv = ws;
  float* P   = ws + 4194304;
  float* rn  = ws + 29360128;
  float* araw = ws + 33554432;
  float* Acum = ws + 33587200;

  unsigned short* xb    = (unsigned short*)(ws + 12582912);
  unsigned short* Wqkvb = (unsigned short*)(ws + 16777216);
  unsigned short* qb    = (unsigned short*)(ws + 12582912);
  unsigned short* kb    = (unsigned short*)(ws + 14680064);
  unsigned short* vb    = (unsigned short*)(ws + 16777216);
  unsigned short* kT_s  = (unsigned short*)(ws + 18874368);
  unsigned short* vT_b  = (unsigned short*)(ws + 20971520);
  unsigned short* stT_b = (unsigned short*)(ws + 23068672);
  unsigned short* rnb   = (unsigned short*)(ws + 25165824);
  unsigned short* Wgateb = (unsigned short*)(ws + 14680064);
  unsigned short* Woutb  = (unsigned short*)(ws + 16777216);
  unsigned short* Hb     = (unsigned short*)(ws + 18874368);

  float* out = (float*)d_out;
  float* out_state = out + 4194304;

  dim3 blk(256);
  f2b2_kernel<<<dim3(16384), blk, 0, stream>>>((const float4*)x, (ushort4*)xb,
                                               (const float4*)W_qkv, (ushort4*)Wqkvb, 4096);
  // qkv GEMM: 256x256 8-phase pipelined kernel (512 threads, grid 24x8 = 192 wg)
  gemm256_nt<<<dim3(24, 8), dim3(512), 0, stream>>>(xb, Wqkvb, qkv, 2048, 6144, 2048);

  alpha_kernel<<<dim3(512), blk, 0, stream>>>(x, W_alpha, b_alpha, alpha_base, araw);
  cumsum_kernel<<<dim3(16), blk, 0, stream>>>(araw, Acum);
  xpos_kernel<<<dim3(8192), blk, 0, stream>>>(qkv, araw, offset, qb, kb, vb);
  transpose_kv_kernel<<<dim3(32, 2, 32), blk, 0, stream>>>(kb, vb, Acum, kT_s, vT_b);
  transpose_state_kernel<<<dim3(2, 2, 16), blk, 0, stream>>>(state, stT_b);

  retention_mfma<<<dim3(16, 32), blk, 0, stream>>>(qb, kb, vT_b, stT_b, Acum,
                                                   gn_w, gn_b, rn, rnb);
  state_gemm<<<dim3(8, 16), blk, 0, stream>>>(kT_s, vT_b, P);
  state_combine<<<dim3(1024), blk, 0, stream>>>(P, state, Acum, out_state);

  f2b2_kernel<<<dim3(8192), blk, 0, stream>>>((const float4*)W_gate, (ushort4*)Wgateb,
                                              (const float4*)W_out, (ushort4*)Woutb, 4096);
  gemm_swish_nt<<<dim3(16, 16), blk, 0, stream>>>(rnb, Wgateb, rn, Hb, 2048, 2048, 2048);
  gemm_bf16_nt<<<dim3(16, 16), blk, 0, stream>>>(Hb, Woutb, out, 2048, 2048, 2048);
}